// Round 6
// baseline (1385.095 us; speedup 1.0000x reference)
//
#include <hip/hip_runtime.h>
#include <hip/hip_bf16.h>
#include <math.h>

// GATNet: hh = h@W_emb+b_emb -> GAT(8 heads,32,residual) -> GAT(1 head,32) -> out f32.
// Edge-feature branch of the reference is dead code (del e_feat) -> skipped.
// R17: megakernel with CHEAP hierarchical barrier. R16 was correct but 450us: the flat
// barrier did 1024 same-line device-scope RMW arrivals (+RMW spin probes) ~33us/barrier
// x9 = ~300us. Fix: (a) 32-shard tree arrival, 128B-padded counter lines (32 parallel
// lines x 32 RMWs + 32-RMW root); (b) spin via __hip_atomic_load (coherent LOADs
// pipeline; RMWs serialize) + s_sleep backoff + bounded guard; (c) scan || B-swizzle ||
// h-cvt merged into one phase -> 8 barriers. Phase math bit-identical to R14/R16.

#define HDIM 256
#define ODIM 32

typedef unsigned short u16;
typedef __attribute__((ext_vector_type(8))) short short8;
typedef __attribute__((ext_vector_type(4))) float f32x4;

__device__ __forceinline__ float bf2f(u16 u) { return __uint_as_float(((unsigned)u) << 16); }
__device__ __forceinline__ u16 f2bf(float f) {
    unsigned x = __float_as_uint(f);
    return (u16)((x + 0x7FFFu + ((x >> 16) & 1u)) >> 16);  // RNE
}
// exp(leaky_relu(l)); logits O(0.1), max-subtraction unnecessary (identical ratios)
__device__ __forceinline__ float edgew(float l) {
    l = (l > 0.f) ? l : 0.2f * l;
    l = fminf(fmaxf(l, -30.f), 30.f);
    return __expf(l);
}

// Hierarchical grid barrier. bar layout (ints, 32-int = 128B stride per counter):
//   leaf_cnt[s] = bar + s*32        (s = bid & 31)
//   leaf_gen[s] = bar + (32+s)*32
//   root_cnt    = bar + 64*32
//   root_gen    = bar + 65*32
// Monotonic counters (zeroed once by memset). Spin uses coherent LOADs, not RMWs.
__device__ __forceinline__ void gbar(int* bar, int nb, int it) {
    __syncthreads();
    if (threadIdx.x == 0) {
        const int bid = (int)blockIdx.x;
        const int shard = bid & 31;
        int* leaf_cnt = bar + shard * 32;
        int* leaf_gen = bar + (32 + shard) * 32;
        int* root_cnt = bar + 64 * 32;
        int* root_gen = bar + 65 * 32;
        const int nshard = (nb < 32) ? nb : 32;
        const int members = (nb - shard + 31) >> 5;  // #bids in [0,nb) with bid&31==shard
        __threadfence();  // release prior data writes
        int prev = __hip_atomic_fetch_add(leaf_cnt, 1, __ATOMIC_ACQ_REL, __HIP_MEMORY_SCOPE_AGENT);
        if (prev == members * (it + 1) - 1) {  // leaf closer
            int rprev = __hip_atomic_fetch_add(root_cnt, 1, __ATOMIC_ACQ_REL, __HIP_MEMORY_SCOPE_AGENT);
            if (rprev == nshard * (it + 1) - 1) {
                __hip_atomic_store(root_gen, it + 1, __ATOMIC_RELEASE, __HIP_MEMORY_SCOPE_AGENT);
            } else {
                long guard = 0;
                while (__hip_atomic_load(root_gen, __ATOMIC_ACQUIRE, __HIP_MEMORY_SCOPE_AGENT) < it + 1) {
                    __builtin_amdgcn_s_sleep(2);
                    if (++guard > (1L << 20)) break;  // safety valve: terminate, don't hang
                }
            }
            __hip_atomic_store(leaf_gen, it + 1, __ATOMIC_RELEASE, __HIP_MEMORY_SCOPE_AGENT);
        } else {
            long guard = 0;
            while (__hip_atomic_load(leaf_gen, __ATOMIC_ACQUIRE, __HIP_MEMORY_SCOPE_AGENT) < it + 1) {
                __builtin_amdgcn_s_sleep(2);
                if (++guard > (1L << 20)) break;
            }
        }
        __threadfence();  // acquire for subsequent data reads
    }
    __syncthreads();
}

struct MegaP {
    const float *in_h, *W_emb, *fc1w, *fc2w;
    const int *src, *dst;
    const float *bemb, *al1, *ar1, *g1, *b1, *al2, *ar2, *g2, *b2;
    int* deg;
    float* stats;   // 512 floats; stats2 = stats+512 (64); then barrier block
    float* stats2;
    int* bar;
    int *offs, *cursor, *srcs;
    u16 *Ah, *Bemb, *Bfc1, *Bfc2;
    u16 *hh, *feat1, *el1, *er1, *rst;
    float *feat2, *el2, *er2, *rst2, *out;
    int N, E, n4, NB16, NBF;
};

__global__ __launch_bounds__(256, 4) void mega(MegaP p) {
    __shared__ alignas(16) unsigned char smem[8192];
    const int t = threadIdx.x;
    const int bid = (int)blockIdx.x;
    const int GRID = (int)gridDim.x;
    const int gtid = bid * 256 + t;
    const int GT = GRID * 256;
    int bi = 0;  // barrier index

    // ================= P0: degree count =================
    for (int i = gtid; i < p.E; i += GT) {
        unsigned d = (unsigned)p.dst[i];
        if (d < (unsigned)p.N) atomicAdd(&p.deg[d], 1);
    }
    gbar(p.bar, GRID, bi++);

    // ========== P1: block0 CSR scan || others {B-swizzles, h->bf16 cvt} ==========
    if (bid == 0) {
        int* wsum = (int*)smem;
        const int n = p.N;
        int chunk = (n + 255) / 256;
        int lo = t * chunk, hi = lo + chunk;
        if (hi > n) hi = n;
        if (lo > n) lo = n;
        int s = 0;
        for (int i = lo; i < hi; i++) s += p.deg[i];
        int v = s;
#pragma unroll
        for (int d = 1; d < 64; d <<= 1) {
            int nb = __shfl_up(v, d, 64);
            if ((t & 63) >= d) v += nb;
        }
        if ((t & 63) == 63) wsum[t >> 6] = v;
        __syncthreads();
        int woff = 0;
#pragma unroll
        for (int w = 0; w < 4; w++)
            if (w < (t >> 6)) woff += wsum[w];
        int run = woff + v - s;
        for (int i = lo; i < hi; i++) {
            p.offs[i] = run;
            p.cursor[i] = run;
            run += p.deg[i];
        }
        if (t == 255) p.offs[n] = run;
    } else {
        // units: 0..51 B-swizzles (Bemb 16, Bfc1 32, Bfc2 4), 52.. h-cvt (256 float4 each)
        const int NCVT = (p.n4 + 255) / 256;
        for (int u = bid - 1; u < 52 + NCVT; u += GRID - 1) {
            if (u >= 52) {
                int idx = (u - 52) * 256 + t;
                if (idx < p.n4) {
                    float4 v = ((const float4*)p.in_h)[idx];
                    ushort4 o = {f2bf(v.x), f2bf(v.y), f2bf(v.z), f2bf(v.w)};
                    ((ushort4*)p.Ah)[idx] = o;
                }
                continue;
            }
            const float* B; u16* O; int K, NC, ub;
            if (u < 16) { B = p.W_emb; O = p.Bemb; K = 128; NC = 256; ub = u; }
            else if (u < 48) { B = p.fc1w; O = p.Bfc1; K = 256; NC = 256; ub = u - 16; }
            else { B = p.fc2w; O = p.Bfc2; K = 256; NC = 32; ub = u - 48; }
            int idx = ub * 256 + t;
            int KB = K / 32;
            int TOT = (NC / 16) * KB * 64;
            if (idx < TOT) {
                int lane = idx & 63;
                int kb = (idx >> 6) % KB;
                int ct = (idx >> 6) / KB;
                int nn = ct * 16 + (lane & 15);
                int k0 = kb * 32 + (lane >> 4) * 8;
                u16* dstp = O + (size_t)idx * 8;
#pragma unroll
                for (int j = 0; j < 8; j++) dstp[j] = f2bf(B[(size_t)(k0 + j) * NC + nn]);
            }
        }
    }
    gbar(p.bar, GRID, bi++);

    // ================= P2: emb->fc1 GEMM tiles + CSR fill =================
    for (int u = bid; u < p.NB16 + p.NBF; u += GRID) {
        if (u >= p.NB16) {  // CSR fill unit (block-uniform branch)
            int i = (u - p.NB16) * 256 + t;
            if (i < p.E) {
                unsigned d = (unsigned)p.dst[i];
                if (d < (unsigned)p.N) {
                    int pp = atomicAdd(&p.cursor[d], 1);
                    if ((unsigned)pp < (unsigned)p.E) p.srcs[pp] = p.src[i];
                }
            }
            continue;
        }
        u16* tile = (u16*)smem;  // 8 KB: swizzled hh tile, then plain feat1 tile
        const int lane = t & 63, w = t >> 6;
        const int rb = u * 16;
        const int m = lane & 15, q = lane >> 4;
        const int arow = rb + m;
        const int M = p.N;
        // stage 1: emb GEMM (K=128), wave w owns ct = w*4..w*4+3
        short8 a0[4];
#pragma unroll
        for (int kb = 0; kb < 4; kb++) {
            if (arow < M) a0[kb] = *(const short8*)(p.Ah + (size_t)arow * 128 + kb * 32 + q * 8);
            else a0[kb] = (short8){0, 0, 0, 0, 0, 0, 0, 0};
        }
        const short8* B8 = (const short8*)p.Bemb;
#pragma unroll
        for (int ct2 = 0; ct2 < 4; ct2++) {
            const int ct = w * 4 + ct2;
            f32x4 acc = {0.f, 0.f, 0.f, 0.f};
#pragma unroll
            for (int kb = 0; kb < 4; kb++)
                acc = __builtin_amdgcn_mfma_f32_16x16x32_bf16(a0[kb], B8[(ct * 4 + kb) * 64 + lane], acc, 0, 0, 0);
            float bv = p.bemb[ct * 16 + m];
#pragma unroll
            for (int r = 0; r < 4; r++) {
                int rl = q * 4 + r;
                int ro = rb + rl;
                u16 hv = 0;
                if (ro < M) {
                    hv = f2bf(acc[r] + bv);
                    p.hh[(size_t)ro * 256 + ct * 16 + m] = hv;
                }
                int byte = rl * 512 + (ct * 16 + m) * 2;
                tile[(byte ^ ((rl & 7) << 4)) >> 1] = hv;  // XOR-swizzle
            }
        }
        __syncthreads();
        // stage 2: fc1 A-fragments from LDS
        short8 af[8];
        {
            int rl = m;
#pragma unroll
            for (int kb = 0; kb < 8; kb++) {
                int byte = rl * 512 + kb * 64 + q * 16;
                af[kb] = *(const short8*)(tile + ((byte ^ ((rl & 7) << 4)) >> 1));
            }
        }
        __syncthreads();
        const short8* Bf = (const short8*)p.Bfc1;
#pragma unroll
        for (int ct2 = 0; ct2 < 4; ct2++) {
            const int ct = w * 4 + ct2;
            f32x4 acc = {0.f, 0.f, 0.f, 0.f};
#pragma unroll
            for (int kb = 0; kb < 8; kb++)
                acc = __builtin_amdgcn_mfma_f32_16x16x32_bf16(af[kb], Bf[(ct * 8 + kb) * 64 + lane], acc, 0, 0, 0);
#pragma unroll
            for (int r = 0; r < 4; r++) {
                int rl = q * 4 + r;
                int ro = rb + rl;
                u16 v = 0;
                if (ro < M) {
                    v = f2bf(acc[r]);
                    p.feat1[(size_t)ro * 256 + ct * 16 + m] = v;
                }
                tile[rl * 256 + ct * 16 + m] = v;  // plain layout for elr epilogue
            }
        }
        __syncthreads();
        // stage 3: el/er epilogue (16 nodes x 8 heads)
        if (t < 128) {
            int nl = t >> 3, h2 = t & 7;
            int node = rb + nl;
            if (node < M) {
                float a_ = 0.f, b_ = 0.f;
#pragma unroll
                for (int d = 0; d < 32; d++) {
                    float fv = bf2f(tile[nl * 256 + h2 * 32 + d]);
                    a_ += fv * p.al1[h2 * 32 + d];
                    b_ += fv * p.ar1[h2 * 32 + d];
                }
                p.el1[node * 8 + h2] = f2bf(a_);
                p.er1[node * 8 + h2] = f2bf(b_);
            }
        }
        __syncthreads();  // tile reuse safety if block loops
    }
    gbar(p.bar, GRID, bi++);

    // ================= P3: agg1 =================
    {
        const int NU = (p.N + 3) >> 2;
        for (int u = bid; u < NU; u += GRID) {
            const int node = u * 4 + (t >> 6);
            const int lane = t & 63;
            if (node < p.N) {
                const int h = lane >> 3;
                int beg = p.offs[node], end = p.offs[node + 1];
                if (beg < 0) beg = 0;
                if (end > p.E) end = p.E;
                float ern = bf2f(p.er1[node * 8 + h]);
                float ax = 0.f, ay = 0.f, az = 0.f, aw = 0.f, sw = 0.f;
                int j = beg;
                int end4 = beg + ((end - beg) & ~3);
                for (; j < end4; j += 4) {
                    int s0 = p.srcs[j], s1 = p.srcs[j + 1], s2 = p.srcs[j + 2], s3 = p.srcs[j + 3];
                    unsigned c0 = (unsigned)s0 < (unsigned)p.N, c1 = (unsigned)s1 < (unsigned)p.N;
                    unsigned c2 = (unsigned)s2 < (unsigned)p.N, c3 = (unsigned)s3 < (unsigned)p.N;
                    s0 = c0 ? s0 : 0; s1 = c1 ? s1 : 0; s2 = c2 ? s2 : 0; s3 = c3 ? s3 : 0;
                    u16 e0 = p.el1[s0 * 8 + h], e1 = p.el1[s1 * 8 + h];
                    u16 e2 = p.el1[s2 * 8 + h], e3 = p.el1[s3 * 8 + h];
                    ushort4 f0 = *(const ushort4*)(p.feat1 + (size_t)s0 * 256 + lane * 4);
                    ushort4 f1 = *(const ushort4*)(p.feat1 + (size_t)s1 * 256 + lane * 4);
                    ushort4 f2 = *(const ushort4*)(p.feat1 + (size_t)s2 * 256 + lane * 4);
                    ushort4 f3 = *(const ushort4*)(p.feat1 + (size_t)s3 * 256 + lane * 4);
                    float w0 = c0 ? edgew(bf2f(e0) + ern) : 0.f;
                    float w1 = c1 ? edgew(bf2f(e1) + ern) : 0.f;
                    float w2 = c2 ? edgew(bf2f(e2) + ern) : 0.f;
                    float w3 = c3 ? edgew(bf2f(e3) + ern) : 0.f;
                    sw += w0 + w1 + w2 + w3;
                    ax += w0 * bf2f(f0.x) + w1 * bf2f(f1.x) + w2 * bf2f(f2.x) + w3 * bf2f(f3.x);
                    ay += w0 * bf2f(f0.y) + w1 * bf2f(f1.y) + w2 * bf2f(f2.y) + w3 * bf2f(f3.y);
                    az += w0 * bf2f(f0.z) + w1 * bf2f(f1.z) + w2 * bf2f(f2.z) + w3 * bf2f(f3.z);
                    aw += w0 * bf2f(f0.w) + w1 * bf2f(f1.w) + w2 * bf2f(f2.w) + w3 * bf2f(f3.w);
                }
                for (; j < end; j++) {
                    int s = p.srcs[j];
                    if ((unsigned)s >= (unsigned)p.N) continue;
                    float wv = edgew(bf2f(p.el1[s * 8 + h]) + ern);
                    ushort4 f4 = *(const ushort4*)(p.feat1 + (size_t)s * 256 + lane * 4);
                    sw += wv;
                    ax += wv * bf2f(f4.x);
                    ay += wv * bf2f(f4.y);
                    az += wv * bf2f(f4.z);
                    aw += wv * bf2f(f4.w);
                }
                float inv = 1.f / (sw + 1e-16f);
                ushort4 o;
                o.x = f2bf(ax * inv); o.y = f2bf(ay * inv);
                o.z = f2bf(az * inv); o.w = f2bf(aw * inv);
                *(ushort4*)(p.rst + (size_t)node * 256 + lane * 4) = o;
            }
        }
    }
    gbar(p.bar, GRID, bi++);

    // ================= P4: bn stats over rst (256 cols) =================
    {
        const int NU = (p.N + 39) / 40;
        for (int u = bid; u < NU; u += GRID) {
            int rbeg = u * 40;
            int rend = rbeg + 40;
            if (rend > p.N) rend = p.N;
            float s = 0.f, s2 = 0.f;
            for (int r = rbeg; r < rend; r++) {
                float x = bf2f(p.rst[(size_t)r * 256 + t]);
                s += x;
                s2 += x * x;
            }
            atomicAdd(&p.stats[t], s);
            atomicAdd(&p.stats[256 + t], s2);
        }
    }
    gbar(p.bar, GRID, bi++);

    // ================= P5: fc2 GEMM (bn_apply1+residual fused) + elr2 =================
    {
        const float invN = 1.f / p.N;
        float* sc = (float*)smem;        // 256
        float* sh = sc + 256;            // 256
        float* red = sh + 256;           // 512
        float* tl = red + 512;           // 512
        const int M = p.N;
        for (int u = bid; u < p.NB16; u += GRID) {
            {
                float mu = p.stats[t] * invN;
                float var = fmaxf(p.stats[256 + t] * invN - mu * mu, 0.f);
                float s = p.g1[t] * rsqrtf(var + 1e-5f);
                sc[t] = s;
                sh[t] = p.b1[t] - mu * s;
            }
            __syncthreads();
            const int lane = t & 63, w = t >> 6;
            const int ct = w & 1, kh = w >> 1;
            const int rb = u * 16;
            const int m = lane & 15, q = lane >> 4;
            const int row = rb + m;
            short8 a[4];
#pragma unroll
            for (int j = 0; j < 4; j++) {
                if (row < M) {
                    int k0 = (kh * 4 + j) * 32 + q * 8;
                    ushort4 r01 = *(const ushort4*)(p.rst + (size_t)row * 256 + k0);
                    ushort4 r23 = *(const ushort4*)(p.rst + (size_t)row * 256 + k0 + 4);
                    ushort4 h01 = *(const ushort4*)(p.hh + (size_t)row * 256 + k0);
                    ushort4 h23 = *(const ushort4*)(p.hh + (size_t)row * 256 + k0 + 4);
                    u16 rv[8] = {r01.x, r01.y, r01.z, r01.w, r23.x, r23.y, r23.z, r23.w};
                    u16 hv[8] = {h01.x, h01.y, h01.z, h01.w, h23.x, h23.y, h23.z, h23.w};
                    short8 av;
#pragma unroll
                    for (int jj = 0; jj < 8; jj++) {
                        int c = k0 + jj;
                        float y = sc[c] * bf2f(rv[jj]) + sh[c];
                        y = (y > 0.f) ? y : expm1f(y);
                        av[jj] = (short)f2bf(bf2f(hv[jj]) + y);
                    }
                    a[j] = av;
                } else a[j] = (short8){0, 0, 0, 0, 0, 0, 0, 0};
            }
            const short8* B8 = (const short8*)p.Bfc2;
            f32x4 acc = {0.f, 0.f, 0.f, 0.f};
#pragma unroll
            for (int j = 0; j < 4; j++)
                acc = __builtin_amdgcn_mfma_f32_16x16x32_bf16(a[j], B8[(ct * 8 + kh * 4 + j) * 64 + lane], acc, 0, 0, 0);
            if (kh == 1) *(f32x4*)&red[ct * 256 + lane * 4] = acc;
            __syncthreads();
            if (kh == 0) {
                f32x4 pp = *(const f32x4*)&red[ct * 256 + lane * 4];
#pragma unroll
                for (int r = 0; r < 4; r++) {
                    int rl = q * 4 + r;
                    int ro = rb + rl;
                    float v = 0.f;
                    if (ro < M) {
                        v = acc[r] + pp[r];
                        p.feat2[(size_t)ro * 32 + ct * 16 + m] = v;
                    }
                    tl[rl * 32 + ct * 16 + m] = v;
                }
            }
            __syncthreads();
            if (t < 16) {
                int node = rb + t;
                if (node < M) {
                    float a_ = 0.f, b_ = 0.f;
#pragma unroll
                    for (int d = 0; d < 32; d++) {
                        float fv = tl[t * 32 + d];
                        a_ += fv * p.al2[d];
                        b_ += fv * p.ar2[d];
                    }
                    p.el2[node] = a_;
                    p.er2[node] = b_;
                }
            }
            __syncthreads();  // smem reuse safety
        }
    }
    gbar(p.bar, GRID, bi++);

    // ================= P6: agg2 =================
    {
        const int NU = (p.N + 7) >> 3;
        for (int u = bid; u < NU; u += GRID) {
            const int node = u * 8 + (t >> 5);
            const int d = t & 31;
            if (node < p.N) {
                int beg = p.offs[node], end = p.offs[node + 1];
                if (beg < 0) beg = 0;
                if (end > p.E) end = p.E;
                float ern = p.er2[node];
                float acc = 0.f, sw = 0.f;
#pragma unroll 2
                for (int j = beg; j < end; j++) {
                    int s = p.srcs[j];
                    if ((unsigned)s >= (unsigned)p.N) continue;
                    float wv = edgew(p.el2[s] + ern);
                    sw += wv;
                    acc += wv * p.feat2[(size_t)s * 32 + d];
                }
                p.rst2[(size_t)node * 32 + d] = acc / (sw + 1e-16f);
            }
        }
    }
    gbar(p.bar, GRID, bi++);

    // ================= P7: bn stats over rst2 (32 cols) =================
    {
        float* ss = (float*)smem;    // 256
        float* ss2 = ss + 256;       // 256
        const int NU = (p.N + 63) >> 6;
        for (int u = bid; u < NU; u += GRID) {
            int c = t & 31, rs = t >> 5;
            int rbeg = u * 64;
            int rend = rbeg + 64;
            if (rend > p.N) rend = p.N;
            float s = 0.f, s2 = 0.f;
            for (int r = rbeg + rs; r < rend; r += 8) {
                float x = p.rst2[(size_t)r * 32 + c];
                s += x;
                s2 += x * x;
            }
            ss[t] = s;
            ss2[t] = s2;
            __syncthreads();
            if (t < 32) {
                for (int j = 32; j < 256; j += 32) { s += ss[t + j]; s2 += ss2[t + j]; }
                atomicAdd(&p.stats2[c], s);
                atomicAdd(&p.stats2[32 + c], s2);
            }
            __syncthreads();
        }
    }
    gbar(p.bar, GRID, bi++);

    // ================= P8: final bn + elu -> out =================
    {
        const float invN = 1.f / p.N;
        const int total = p.N * 32;
        for (int i = gtid; i < total; i += GT) {
            int c = i & 31;
            float mu = p.stats2[c] * invN;
            float var = fmaxf(p.stats2[32 + c] * invN - mu * mu, 0.f);
            float y = p.g2[c] * (p.rst2[i] - mu) * rsqrtf(var + 1e-5f) + p.b2[c];
            y = (y > 0.f) ? y : expm1f(y);
            p.out[i] = y;
        }
    }
}

extern "C" void kernel_launch(void* const* d_in, const int* in_sizes, int n_in, void* d_out, int out_size, void* d_ws,
                              size_t ws_size, hipStream_t stream) {
    const int N = out_size / ODIM;
    const int E = in_sizes[2];

    MegaP P;
    P.in_h = (const float*)d_in[0];
    P.src = (const int*)d_in[2];
    P.dst = (const int*)d_in[3];
    P.W_emb = (const float*)d_in[4];  P.bemb = (const float*)d_in[5];
    P.fc1w = (const float*)d_in[18];  P.al1 = (const float*)d_in[19];
    P.ar1 = (const float*)d_in[20];
    P.g1 = (const float*)d_in[21];    P.b1 = (const float*)d_in[22];
    P.fc2w = (const float*)d_in[23];  P.al2 = (const float*)d_in[24];
    P.ar2 = (const float*)d_in[25];
    P.g2 = (const float*)d_in[26];    P.b2 = (const float*)d_in[27];
    P.out = (float*)d_out;

    // ---- ws layout (~26 MB) ----
    char* base = (char*)d_ws;
    size_t off = 0;
    auto alloc = [&](size_t bytes) { void* p = base + off; off += (bytes + 63) & ~63ull; return p; };
    const size_t BARB = 66 * 32 * 4;  // 66 x 128B counter lines
    const size_t ZBYTES = (size_t)N * 4 + 512 * 4 + 64 * 4 + BARB;
    char* zb = (char*)alloc(ZBYTES);
    P.deg = (int*)zb;
    P.stats = (float*)(zb + (size_t)N * 4);
    P.stats2 = P.stats + 512;
    P.bar = (int*)(P.stats2 + 64);
    P.offs = (int*)alloc((size_t)(N + 1) * 4);
    P.cursor = (int*)alloc((size_t)N * 4);
    P.srcs = (int*)alloc((size_t)E * 4);
    P.Ah = (u16*)alloc((size_t)N * 128 * 2);
    P.Bemb = (u16*)alloc((size_t)128 * 256 * 2);
    P.Bfc1 = (u16*)alloc((size_t)256 * 256 * 2);
    P.Bfc2 = (u16*)alloc((size_t)256 * 32 * 2);
    P.hh = (u16*)alloc((size_t)N * HDIM * 2);
    P.feat1 = (u16*)alloc((size_t)N * HDIM * 2);
    P.el1 = (u16*)alloc((size_t)N * 8 * 2);
    P.er1 = (u16*)alloc((size_t)N * 8 * 2);
    P.rst = (u16*)alloc((size_t)N * HDIM * 2);
    P.feat2 = (float*)alloc((size_t)N * 32 * 4);
    P.el2 = (float*)alloc((size_t)N * 4);
    P.er2 = (float*)alloc((size_t)N * 4);
    P.rst2 = (float*)alloc((size_t)N * 32 * 4);

    P.N = N;
    P.E = E;
    P.n4 = N * 32;            // N*128/4 float4 groups
    P.NB16 = (N + 15) / 16;   // GEMM tile units
    P.NBF = (E + 255) / 256;  // fill units

    // occupancy-clamped grid: all blocks MUST be co-resident for gbar. Query once.
    static int g_grid = 0;
    if (g_grid == 0) {
        int nb = 0;
        hipError_t e =
            hipOccupancyMaxActiveBlocksPerMultiprocessor(&nb, reinterpret_cast<const void*>(mega), 256, 0);
        if (e != hipSuccess || nb < 1) nb = 1;
        if (nb > 4) nb = 4;
        g_grid = nb * 256;  // gfx950: 256 CUs
    }

    hipMemsetAsync(zb, 0, ZBYTES, stream);
    mega<<<dim3(g_grid), dim3(256), 0, stream>>>(P);
}

// Round 7
// 446.565 us; speedup vs baseline: 3.1017x; 3.1017x over previous
//
#include <hip/hip_runtime.h>
#include <hip/hip_bf16.h>
#include <math.h>

// GATNet: hh = h@W_emb+b_emb -> GAT(8 heads,32,residual) -> GAT(1 head,32) -> out f32.
// Edge-feature branch of the reference is dead code (del e_feat) -> skipped.
// R18: megakernel, barrier attempt 3. R16 flat-RMW barrier: ~33us each (same-line RMW
// serialization). R17 acquire-load spin: ~230us each — agent-scope ACQUIRE loads emit
// a buffer_inv (L2 invalidate) PER PROBE on gfx950; 1023 spinners = invalidate storm
// stalling all memory traffic (VALUBusy 0.7%, HBM 0.7%, traffic counters unchanged).
// Fix: fence-to-fence sync. threadfence (release) -> RELAXED tree arrivals -> RELAXED
// load spin with stepped s_sleep backoff -> ONE threadfence (acquire, single inv) at
// exit. <=32 spinners per line (32-shard tree). Phases byte-identical to R17.

#define HDIM 256
#define ODIM 32

typedef unsigned short u16;
typedef __attribute__((ext_vector_type(8))) short short8;
typedef __attribute__((ext_vector_type(4))) float f32x4;

__device__ __forceinline__ float bf2f(u16 u) { return __uint_as_float(((unsigned)u) << 16); }
__device__ __forceinline__ u16 f2bf(float f) {
    unsigned x = __float_as_uint(f);
    return (u16)((x + 0x7FFFu + ((x >> 16) & 1u)) >> 16);  // RNE
}
// exp(leaky_relu(l)); logits O(0.1), max-subtraction unnecessary (identical ratios)
__device__ __forceinline__ float edgew(float l) {
    l = (l > 0.f) ? l : 0.2f * l;
    l = fminf(fmaxf(l, -30.f), 30.f);
    return __expf(l);
}

__device__ __forceinline__ int relax_load(int* pp) {
    return __hip_atomic_load(pp, __ATOMIC_RELAXED, __HIP_MEMORY_SCOPE_AGENT);
}
// stepped backoff spin (s_sleep needs immediate operands)
__device__ __forceinline__ void spin_until(int* pp, int target) {
    long guard = 0;
    int step = 0;
    while (relax_load(pp) < target) {
        if (step < 8) __builtin_amdgcn_s_sleep(1);
        else if (step < 64) __builtin_amdgcn_s_sleep(8);
        else __builtin_amdgcn_s_sleep(32);
        step++;
        if (++guard > (1L << 20)) break;  // safety valve: terminate, don't hang
    }
}

// Hierarchical grid barrier. bar layout (ints, 32-int = 128B stride per counter):
//   leaf_cnt[s] = bar + s*32   leaf_gen[s] = bar + (32+s)*32   (s = bid & 31)
//   root_cnt = bar + 64*32     root_gen = bar + 65*32
// Monotonic counters zeroed once by memset. All sync via fence-to-fence: release
// threadfence before arrival, RELAXED RMWs/loads, acquire threadfence after exit.
__device__ __forceinline__ void gbar(int* bar, int nb, int it) {
    __syncthreads();
    if (threadIdx.x == 0) {
        const int bid = (int)blockIdx.x;
        const int shard = bid & 31;
        int* leaf_cnt = bar + shard * 32;
        int* leaf_gen = bar + (32 + shard) * 32;
        int* root_cnt = bar + 64 * 32;
        int* root_gen = bar + 65 * 32;
        const int nshard = (nb < 32) ? nb : 32;
        const int members = (nb - shard + 31) >> 5;  // #bids in [0,nb) with bid&31==shard
        __threadfence();  // release prior data writes
        int prev = __hip_atomic_fetch_add(leaf_cnt, 1, __ATOMIC_RELAXED, __HIP_MEMORY_SCOPE_AGENT);
        if (prev == members * (it + 1) - 1) {  // leaf closer
            int rprev = __hip_atomic_fetch_add(root_cnt, 1, __ATOMIC_RELAXED, __HIP_MEMORY_SCOPE_AGENT);
            if (rprev == nshard * (it + 1) - 1) {
                __hip_atomic_store(root_gen, it + 1, __ATOMIC_RELAXED, __HIP_MEMORY_SCOPE_AGENT);
            } else {
                spin_until(root_gen, it + 1);
            }
            __hip_atomic_store(leaf_gen, it + 1, __ATOMIC_RELAXED, __HIP_MEMORY_SCOPE_AGENT);
        } else {
            spin_until(leaf_gen, it + 1);
        }
        __threadfence();  // acquire: one invalidate, subsequent reads see fresh data
    }
    __syncthreads();
}

struct MegaP {
    const float *in_h, *W_emb, *fc1w, *fc2w;
    const int *src, *dst;
    const float *bemb, *al1, *ar1, *g1, *b1, *al2, *ar2, *g2, *b2;
    int* deg;
    float* stats;   // 512 floats; stats2 = stats+512 (64); then barrier block
    float* stats2;
    int* bar;
    int *offs, *cursor, *srcs;
    u16 *Ah, *Bemb, *Bfc1, *Bfc2;
    u16 *hh, *feat1, *el1, *er1, *rst;
    float *feat2, *el2, *er2, *rst2, *out;
    int N, E, n4, NB16, NBF;
};

__global__ __launch_bounds__(256, 4) void mega(MegaP p) {
    __shared__ alignas(16) unsigned char smem[8192];
    const int t = threadIdx.x;
    const int bid = (int)blockIdx.x;
    const int GRID = (int)gridDim.x;
    const int gtid = bid * 256 + t;
    const int GT = GRID * 256;
    int bi = 0;  // barrier index

    // ================= P0: degree count =================
    for (int i = gtid; i < p.E; i += GT) {
        unsigned d = (unsigned)p.dst[i];
        if (d < (unsigned)p.N) atomicAdd(&p.deg[d], 1);
    }
    gbar(p.bar, GRID, bi++);

    // ========== P1: block0 CSR scan || others {B-swizzles, h->bf16 cvt} ==========
    if (bid == 0) {
        int* wsum = (int*)smem;
        const int n = p.N;
        int chunk = (n + 255) / 256;
        int lo = t * chunk, hi = lo + chunk;
        if (hi > n) hi = n;
        if (lo > n) lo = n;
        int s = 0;
        for (int i = lo; i < hi; i++) s += p.deg[i];
        int v = s;
#pragma unroll
        for (int d = 1; d < 64; d <<= 1) {
            int nb = __shfl_up(v, d, 64);
            if ((t & 63) >= d) v += nb;
        }
        if ((t & 63) == 63) wsum[t >> 6] = v;
        __syncthreads();
        int woff = 0;
#pragma unroll
        for (int w = 0; w < 4; w++)
            if (w < (t >> 6)) woff += wsum[w];
        int run = woff + v - s;
        for (int i = lo; i < hi; i++) {
            p.offs[i] = run;
            p.cursor[i] = run;
            run += p.deg[i];
        }
        if (t == 255) p.offs[n] = run;
    } else {
        // units: 0..51 B-swizzles (Bemb 16, Bfc1 32, Bfc2 4), 52.. h-cvt (256 float4 each)
        const int NCVT = (p.n4 + 255) / 256;
        for (int u = bid - 1; u < 52 + NCVT; u += GRID - 1) {
            if (u >= 52) {
                int idx = (u - 52) * 256 + t;
                if (idx < p.n4) {
                    float4 v = ((const float4*)p.in_h)[idx];
                    ushort4 o = {f2bf(v.x), f2bf(v.y), f2bf(v.z), f2bf(v.w)};
                    ((ushort4*)p.Ah)[idx] = o;
                }
                continue;
            }
            const float* B; u16* O; int K, NC, ub;
            if (u < 16) { B = p.W_emb; O = p.Bemb; K = 128; NC = 256; ub = u; }
            else if (u < 48) { B = p.fc1w; O = p.Bfc1; K = 256; NC = 256; ub = u - 16; }
            else { B = p.fc2w; O = p.Bfc2; K = 256; NC = 32; ub = u - 48; }
            int idx = ub * 256 + t;
            int KB = K / 32;
            int TOT = (NC / 16) * KB * 64;
            if (idx < TOT) {
                int lane = idx & 63;
                int kb = (idx >> 6) % KB;
                int ct = (idx >> 6) / KB;
                int nn = ct * 16 + (lane & 15);
                int k0 = kb * 32 + (lane >> 4) * 8;
                u16* dstp = O + (size_t)idx * 8;
#pragma unroll
                for (int j = 0; j < 8; j++) dstp[j] = f2bf(B[(size_t)(k0 + j) * NC + nn]);
            }
        }
    }
    gbar(p.bar, GRID, bi++);

    // ================= P2: emb->fc1 GEMM tiles + CSR fill =================
    for (int u = bid; u < p.NB16 + p.NBF; u += GRID) {
        if (u >= p.NB16) {  // CSR fill unit (block-uniform branch)
            int i = (u - p.NB16) * 256 + t;
            if (i < p.E) {
                unsigned d = (unsigned)p.dst[i];
                if (d < (unsigned)p.N) {
                    int pp = atomicAdd(&p.cursor[d], 1);
                    if ((unsigned)pp < (unsigned)p.E) p.srcs[pp] = p.src[i];
                }
            }
            continue;
        }
        u16* tile = (u16*)smem;  // 8 KB: swizzled hh tile, then plain feat1 tile
        const int lane = t & 63, w = t >> 6;
        const int rb = u * 16;
        const int m = lane & 15, q = lane >> 4;
        const int arow = rb + m;
        const int M = p.N;
        // stage 1: emb GEMM (K=128), wave w owns ct = w*4..w*4+3
        short8 a0[4];
#pragma unroll
        for (int kb = 0; kb < 4; kb++) {
            if (arow < M) a0[kb] = *(const short8*)(p.Ah + (size_t)arow * 128 + kb * 32 + q * 8);
            else a0[kb] = (short8){0, 0, 0, 0, 0, 0, 0, 0};
        }
        const short8* B8 = (const short8*)p.Bemb;
#pragma unroll
        for (int ct2 = 0; ct2 < 4; ct2++) {
            const int ct = w * 4 + ct2;
            f32x4 acc = {0.f, 0.f, 0.f, 0.f};
#pragma unroll
            for (int kb = 0; kb < 4; kb++)
                acc = __builtin_amdgcn_mfma_f32_16x16x32_bf16(a0[kb], B8[(ct * 4 + kb) * 64 + lane], acc, 0, 0, 0);
            float bv = p.bemb[ct * 16 + m];
#pragma unroll
            for (int r = 0; r < 4; r++) {
                int rl = q * 4 + r;
                int ro = rb + rl;
                u16 hv = 0;
                if (ro < M) {
                    hv = f2bf(acc[r] + bv);
                    p.hh[(size_t)ro * 256 + ct * 16 + m] = hv;
                }
                int byte = rl * 512 + (ct * 16 + m) * 2;
                tile[(byte ^ ((rl & 7) << 4)) >> 1] = hv;  // XOR-swizzle
            }
        }
        __syncthreads();
        // stage 2: fc1 A-fragments from LDS
        short8 af[8];
        {
            int rl = m;
#pragma unroll
            for (int kb = 0; kb < 8; kb++) {
                int byte = rl * 512 + kb * 64 + q * 16;
                af[kb] = *(const short8*)(tile + ((byte ^ ((rl & 7) << 4)) >> 1));
            }
        }
        __syncthreads();
        const short8* Bf = (const short8*)p.Bfc1;
#pragma unroll
        for (int ct2 = 0; ct2 < 4; ct2++) {
            const int ct = w * 4 + ct2;
            f32x4 acc = {0.f, 0.f, 0.f, 0.f};
#pragma unroll
            for (int kb = 0; kb < 8; kb++)
                acc = __builtin_amdgcn_mfma_f32_16x16x32_bf16(af[kb], Bf[(ct * 8 + kb) * 64 + lane], acc, 0, 0, 0);
#pragma unroll
            for (int r = 0; r < 4; r++) {
                int rl = q * 4 + r;
                int ro = rb + rl;
                u16 v = 0;
                if (ro < M) {
                    v = f2bf(acc[r]);
                    p.feat1[(size_t)ro * 256 + ct * 16 + m] = v;
                }
                tile[rl * 256 + ct * 16 + m] = v;  // plain layout for elr epilogue
            }
        }
        __syncthreads();
        // stage 3: el/er epilogue (16 nodes x 8 heads)
        if (t < 128) {
            int nl = t >> 3, h2 = t & 7;
            int node = rb + nl;
            if (node < M) {
                float a_ = 0.f, b_ = 0.f;
#pragma unroll
                for (int d = 0; d < 32; d++) {
                    float fv = bf2f(tile[nl * 256 + h2 * 32 + d]);
                    a_ += fv * p.al1[h2 * 32 + d];
                    b_ += fv * p.ar1[h2 * 32 + d];
                }
                p.el1[node * 8 + h2] = f2bf(a_);
                p.er1[node * 8 + h2] = f2bf(b_);
            }
        }
        __syncthreads();  // tile reuse safety if block loops
    }
    gbar(p.bar, GRID, bi++);

    // ================= P3: agg1 =================
    {
        const int NU = (p.N + 3) >> 2;
        for (int u = bid; u < NU; u += GRID) {
            const int node = u * 4 + (t >> 6);
            const int lane = t & 63;
            if (node < p.N) {
                const int h = lane >> 3;
                int beg = p.offs[node], end = p.offs[node + 1];
                if (beg < 0) beg = 0;
                if (end > p.E) end = p.E;
                float ern = bf2f(p.er1[node * 8 + h]);
                float ax = 0.f, ay = 0.f, az = 0.f, aw = 0.f, sw = 0.f;
                int j = beg;
                int end4 = beg + ((end - beg) & ~3);
                for (; j < end4; j += 4) {
                    int s0 = p.srcs[j], s1 = p.srcs[j + 1], s2 = p.srcs[j + 2], s3 = p.srcs[j + 3];
                    unsigned c0 = (unsigned)s0 < (unsigned)p.N, c1 = (unsigned)s1 < (unsigned)p.N;
                    unsigned c2 = (unsigned)s2 < (unsigned)p.N, c3 = (unsigned)s3 < (unsigned)p.N;
                    s0 = c0 ? s0 : 0; s1 = c1 ? s1 : 0; s2 = c2 ? s2 : 0; s3 = c3 ? s3 : 0;
                    u16 e0 = p.el1[s0 * 8 + h], e1 = p.el1[s1 * 8 + h];
                    u16 e2 = p.el1[s2 * 8 + h], e3 = p.el1[s3 * 8 + h];
                    ushort4 f0 = *(const ushort4*)(p.feat1 + (size_t)s0 * 256 + lane * 4);
                    ushort4 f1 = *(const ushort4*)(p.feat1 + (size_t)s1 * 256 + lane * 4);
                    ushort4 f2 = *(const ushort4*)(p.feat1 + (size_t)s2 * 256 + lane * 4);
                    ushort4 f3 = *(const ushort4*)(p.feat1 + (size_t)s3 * 256 + lane * 4);
                    float w0 = c0 ? edgew(bf2f(e0) + ern) : 0.f;
                    float w1 = c1 ? edgew(bf2f(e1) + ern) : 0.f;
                    float w2 = c2 ? edgew(bf2f(e2) + ern) : 0.f;
                    float w3 = c3 ? edgew(bf2f(e3) + ern) : 0.f;
                    sw += w0 + w1 + w2 + w3;
                    ax += w0 * bf2f(f0.x) + w1 * bf2f(f1.x) + w2 * bf2f(f2.x) + w3 * bf2f(f3.x);
                    ay += w0 * bf2f(f0.y) + w1 * bf2f(f1.y) + w2 * bf2f(f2.y) + w3 * bf2f(f3.y);
                    az += w0 * bf2f(f0.z) + w1 * bf2f(f1.z) + w2 * bf2f(f2.z) + w3 * bf2f(f3.z);
                    aw += w0 * bf2f(f0.w) + w1 * bf2f(f1.w) + w2 * bf2f(f2.w) + w3 * bf2f(f3.w);
                }
                for (; j < end; j++) {
                    int s = p.srcs[j];
                    if ((unsigned)s >= (unsigned)p.N) continue;
                    float wv = edgew(bf2f(p.el1[s * 8 + h]) + ern);
                    ushort4 f4 = *(const ushort4*)(p.feat1 + (size_t)s * 256 + lane * 4);
                    sw += wv;
                    ax += wv * bf2f(f4.x);
                    ay += wv * bf2f(f4.y);
                    az += wv * bf2f(f4.z);
                    aw += wv * bf2f(f4.w);
                }
                float inv = 1.f / (sw + 1e-16f);
                ushort4 o;
                o.x = f2bf(ax * inv); o.y = f2bf(ay * inv);
                o.z = f2bf(az * inv); o.w = f2bf(aw * inv);
                *(ushort4*)(p.rst + (size_t)node * 256 + lane * 4) = o;
            }
        }
    }
    gbar(p.bar, GRID, bi++);

    // ================= P4: bn stats over rst (256 cols) =================
    {
        const int NU = (p.N + 39) / 40;
        for (int u = bid; u < NU; u += GRID) {
            int rbeg = u * 40;
            int rend = rbeg + 40;
            if (rend > p.N) rend = p.N;
            float s = 0.f, s2 = 0.f;
            for (int r = rbeg; r < rend; r++) {
                float x = bf2f(p.rst[(size_t)r * 256 + t]);
                s += x;
                s2 += x * x;
            }
            atomicAdd(&p.stats[t], s);
            atomicAdd(&p.stats[256 + t], s2);
        }
    }
    gbar(p.bar, GRID, bi++);

    // ================= P5: fc2 GEMM (bn_apply1+residual fused) + elr2 =================
    {
        const float invN = 1.f / p.N;
        float* sc = (float*)smem;        // 256
        float* sh = sc + 256;            // 256
        float* red = sh + 256;           // 512
        float* tl = red + 512;           // 512
        const int M = p.N;
        for (int u = bid; u < p.NB16; u += GRID) {
            {
                float mu = p.stats[t] * invN;
                float var = fmaxf(p.stats[256 + t] * invN - mu * mu, 0.f);
                float s = p.g1[t] * rsqrtf(var + 1e-5f);
                sc[t] = s;
                sh[t] = p.b1[t] - mu * s;
            }
            __syncthreads();
            const int lane = t & 63, w = t >> 6;
            const int ct = w & 1, kh = w >> 1;
            const int rb = u * 16;
            const int m = lane & 15, q = lane >> 4;
            const int row = rb + m;
            short8 a[4];
#pragma unroll
            for (int j = 0; j < 4; j++) {
                if (row < M) {
                    int k0 = (kh * 4 + j) * 32 + q * 8;
                    ushort4 r01 = *(const ushort4*)(p.rst + (size_t)row * 256 + k0);
                    ushort4 r23 = *(const ushort4*)(p.rst + (size_t)row * 256 + k0 + 4);
                    ushort4 h01 = *(const ushort4*)(p.hh + (size_t)row * 256 + k0);
                    ushort4 h23 = *(const ushort4*)(p.hh + (size_t)row * 256 + k0 + 4);
                    u16 rv[8] = {r01.x, r01.y, r01.z, r01.w, r23.x, r23.y, r23.z, r23.w};
                    u16 hv[8] = {h01.x, h01.y, h01.z, h01.w, h23.x, h23.y, h23.z, h23.w};
                    short8 av;
#pragma unroll
                    for (int jj = 0; jj < 8; jj++) {
                        int c = k0 + jj;
                        float y = sc[c] * bf2f(rv[jj]) + sh[c];
                        y = (y > 0.f) ? y : expm1f(y);
                        av[jj] = (short)f2bf(bf2f(hv[jj]) + y);
                    }
                    a[j] = av;
                } else a[j] = (short8){0, 0, 0, 0, 0, 0, 0, 0};
            }
            const short8* B8 = (const short8*)p.Bfc2;
            f32x4 acc = {0.f, 0.f, 0.f, 0.f};
#pragma unroll
            for (int j = 0; j < 4; j++)
                acc = __builtin_amdgcn_mfma_f32_16x16x32_bf16(a[j], B8[(ct * 8 + kh * 4 + j) * 64 + lane], acc, 0, 0, 0);
            if (kh == 1) *(f32x4*)&red[ct * 256 + lane * 4] = acc;
            __syncthreads();
            if (kh == 0) {
                f32x4 pp = *(const f32x4*)&red[ct * 256 + lane * 4];
#pragma unroll
                for (int r = 0; r < 4; r++) {
                    int rl = q * 4 + r;
                    int ro = rb + rl;
                    float v = 0.f;
                    if (ro < M) {
                        v = acc[r] + pp[r];
                        p.feat2[(size_t)ro * 32 + ct * 16 + m] = v;
                    }
                    tl[rl * 32 + ct * 16 + m] = v;
                }
            }
            __syncthreads();
            if (t < 16) {
                int node = rb + t;
                if (node < M) {
                    float a_ = 0.f, b_ = 0.f;
#pragma unroll
                    for (int d = 0; d < 32; d++) {
                        float fv = tl[t * 32 + d];
                        a_ += fv * p.al2[d];
                        b_ += fv * p.ar2[d];
                    }
                    p.el2[node] = a_;
                    p.er2[node] = b_;
                }
            }
            __syncthreads();  // smem reuse safety
        }
    }
    gbar(p.bar, GRID, bi++);

    // ================= P6: agg2 =================
    {
        const int NU = (p.N + 7) >> 3;
        for (int u = bid; u < NU; u += GRID) {
            const int node = u * 8 + (t >> 5);
            const int d = t & 31;
            if (node < p.N) {
                int beg = p.offs[node], end = p.offs[node + 1];
                if (beg < 0) beg = 0;
                if (end > p.E) end = p.E;
                float ern = p.er2[node];
                float acc = 0.f, sw = 0.f;
#pragma unroll 2
                for (int j = beg; j < end; j++) {
                    int s = p.srcs[j];
                    if ((unsigned)s >= (unsigned)p.N) continue;
                    float wv = edgew(p.el2[s] + ern);
                    sw += wv;
                    acc += wv * p.feat2[(size_t)s * 32 + d];
                }
                p.rst2[(size_t)node * 32 + d] = acc / (sw + 1e-16f);
            }
        }
    }
    gbar(p.bar, GRID, bi++);

    // ================= P7: bn stats over rst2 (32 cols) =================
    {
        float* ss = (float*)smem;    // 256
        float* ss2 = ss + 256;       // 256
        const int NU = (p.N + 63) >> 6;
        for (int u = bid; u < NU; u += GRID) {
            int c = t & 31, rs = t >> 5;
            int rbeg = u * 64;
            int rend = rbeg + 64;
            if (rend > p.N) rend = p.N;
            float s = 0.f, s2 = 0.f;
            for (int r = rbeg + rs; r < rend; r += 8) {
                float x = p.rst2[(size_t)r * 32 + c];
                s += x;
                s2 += x * x;
            }
            ss[t] = s;
            ss2[t] = s2;
            __syncthreads();
            if (t < 32) {
                for (int j = 32; j < 256; j += 32) { s += ss[t + j]; s2 += ss2[t + j]; }
                atomicAdd(&p.stats2[c], s);
                atomicAdd(&p.stats2[32 + c], s2);
            }
            __syncthreads();
        }
    }
    gbar(p.bar, GRID, bi++);

    // ================= P8: final bn + elu -> out =================
    {
        const float invN = 1.f / p.N;
        const int total = p.N * 32;
        for (int i = gtid; i < total; i += GT) {
            int c = i & 31;
            float mu = p.stats2[c] * invN;
            float var = fmaxf(p.stats2[32 + c] * invN - mu * mu, 0.f);
            float y = p.g2[c] * (p.rst2[i] - mu) * rsqrtf(var + 1e-5f) + p.b2[c];
            y = (y > 0.f) ? y : expm1f(y);
            p.out[i] = y;
        }
    }
}

extern "C" void kernel_launch(void* const* d_in, const int* in_sizes, int n_in, void* d_out, int out_size, void* d_ws,
                              size_t ws_size, hipStream_t stream) {
    const int N = out_size / ODIM;
    const int E = in_sizes[2];

    MegaP P;
    P.in_h = (const float*)d_in[0];
    P.src = (const int*)d_in[2];
    P.dst = (const int*)d_in[3];
    P.W_emb = (const float*)d_in[4];  P.bemb = (const float*)d_in[5];
    P.fc1w = (const float*)d_in[18];  P.al1 = (const float*)d_in[19];
    P.ar1 = (const float*)d_in[20];
    P.g1 = (const float*)d_in[21];    P.b1 = (const float*)d_in[22];
    P.fc2w = (const float*)d_in[23];  P.al2 = (const float*)d_in[24];
    P.ar2 = (const float*)d_in[25];
    P.g2 = (const float*)d_in[26];    P.b2 = (const float*)d_in[27];
    P.out = (float*)d_out;

    // ---- ws layout (~26 MB) ----
    char* base = (char*)d_ws;
    size_t off = 0;
    auto alloc = [&](size_t bytes) { void* p = base + off; off += (bytes + 63) & ~63ull; return p; };
    const size_t BARB = 66 * 32 * 4;  // 66 x 128B counter lines
    const size_t ZBYTES = (size_t)N * 4 + 512 * 4 + 64 * 4 + BARB;
    char* zb = (char*)alloc(ZBYTES);
    P.deg = (int*)zb;
    P.stats = (float*)(zb + (size_t)N * 4);
    P.stats2 = P.stats + 512;
    P.bar = (int*)(P.stats2 + 64);
    P.offs = (int*)alloc((size_t)(N + 1) * 4);
    P.cursor = (int*)alloc((size_t)N * 4);
    P.srcs = (int*)alloc((size_t)E * 4);
    P.Ah = (u16*)alloc((size_t)N * 128 * 2);
    P.Bemb = (u16*)alloc((size_t)128 * 256 * 2);
    P.Bfc1 = (u16*)alloc((size_t)256 * 256 * 2);
    P.Bfc2 = (u16*)alloc((size_t)256 * 32 * 2);
    P.hh = (u16*)alloc((size_t)N * HDIM * 2);
    P.feat1 = (u16*)alloc((size_t)N * HDIM * 2);
    P.el1 = (u16*)alloc((size_t)N * 8 * 2);
    P.er1 = (u16*)alloc((size_t)N * 8 * 2);
    P.rst = (u16*)alloc((size_t)N * HDIM * 2);
    P.feat2 = (float*)alloc((size_t)N * 32 * 4);
    P.el2 = (float*)alloc((size_t)N * 4);
    P.er2 = (float*)alloc((size_t)N * 4);
    P.rst2 = (float*)alloc((size_t)N * 32 * 4);

    P.N = N;
    P.E = E;
    P.n4 = N * 32;            // N*128/4 float4 groups
    P.NB16 = (N + 15) / 16;   // GEMM tile units
    P.NBF = (E + 255) / 256;  // fill units

    // occupancy-clamped grid: all blocks MUST be co-resident for gbar. Query once.
    static int g_grid = 0;
    if (g_grid == 0) {
        int nb = 0;
        hipError_t e =
            hipOccupancyMaxActiveBlocksPerMultiprocessor(&nb, reinterpret_cast<const void*>(mega), 256, 0);
        if (e != hipSuccess || nb < 1) nb = 1;
        if (nb > 4) nb = 4;
        g_grid = nb * 256;  // gfx950: 256 CUs
    }

    hipMemsetAsync(zb, 0, ZBYTES, stream);
    mega<<<dim3(g_grid), dim3(256), 0, stream>>>(P);
}

// Round 8
// 249.668 us; speedup vs baseline: 5.5477x; 1.7886x over previous
//
#include <hip/hip_runtime.h>
#include <hip/hip_bf16.h>
#include <math.h>

// GATNet: hh = h@W_emb+b_emb -> GAT(8 heads,32,residual) -> GAT(1 head,32) -> out f32.
// Edge-feature branch of the reference is dead code (del e_feat) -> skipped.
// R19: REVERT to R14 multi-dispatch structure (252us verified). Megakernel arc
// (R15-R18) abandoned: two different grid-barrier implementations both landed at
// ~450us -> overhead is NOT barrier mechanics but per-block agent-scope fence cost
// (1024 blocks x L2 wb/inv per phase on 8 non-coherent XCD L2s + cold-cache phase
// restarts). The CP does per-dispatch cache maintenance once per L2; software can't
// beat it in plain HIP. Delta vs R14: agg2 gets the same 4-deep software pipeline
// agg1 has (bit-identical accumulation order; clamped lanes add +0.0f).

#define HDIM 256
#define NHEADS 8
#define ODIM 32

typedef unsigned short u16;
typedef __attribute__((ext_vector_type(8))) short short8;
typedef __attribute__((ext_vector_type(4))) float f32x4;

__device__ __forceinline__ float bf2f(u16 u) { return __uint_as_float(((unsigned)u) << 16); }
__device__ __forceinline__ u16 f2bf(float f) {
    unsigned x = __float_as_uint(f);
    return (u16)((x + 0x7FFFu + ((x >> 16) & 1u)) >> 16);  // RNE
}

// ---------------- prep: batched cvt + B swizzles + deg ----------------
__global__ __launch_bounds__(256) void prep_kernel(const float* __restrict__ in_h, const float* __restrict__ W_emb,
                                                   const float* __restrict__ fc1, const float* __restrict__ fc2,
                                                   const int* __restrict__ dstv, int* __restrict__ deg,
                                                   u16* __restrict__ Ah, u16* __restrict__ Bemb,
                                                   u16* __restrict__ Bfc1, u16* __restrict__ Bfc2,
                                                   int n4, int E, int N) {
    int job = blockIdx.y;
    int idx = blockIdx.x * 256 + threadIdx.x;
    if (job == 0) {
        if (idx >= n4) return;
        float4 v = ((const float4*)in_h)[idx];
        ushort4 o = {f2bf(v.x), f2bf(v.y), f2bf(v.z), f2bf(v.w)};
        ((ushort4*)Ah)[idx] = o;
        return;
    }
    if (job == 4) {  // degree count (independent of cvt jobs; deg pre-zeroed by memset)
        if (idx < E) {
            unsigned d = (unsigned)dstv[idx];
            if (d < (unsigned)N) atomicAdd(&deg[d], 1);
        }
        return;
    }
    const float* B;
    u16* O;
    int K, NC;
    if (job == 1) { B = W_emb; O = Bemb; K = 128; NC = 256; }
    else if (job == 2) { B = fc1; O = Bfc1; K = 256; NC = 256; }
    else { B = fc2; O = Bfc2; K = 256; NC = 32; }
    int KB = K / 32;
    int TOT = (NC / 16) * KB * 64;
    if (idx >= TOT) return;
    int lane = idx & 63;
    int kb = (idx >> 6) % KB;
    int ct = (idx >> 6) / KB;
    int n = ct * 16 + (lane & 15);
    int k0 = kb * 32 + (lane >> 4) * 8;
    u16* dst = O + (size_t)idx * 8;
#pragma unroll
    for (int j = 0; j < 8; j++) dst[j] = f2bf(B[(size_t)(k0 + j) * NC + n]);
}

// ---------------- CSR scan (wave-parallel) ----------------
__global__ __launch_bounds__(256) void scan_kernel(const int* __restrict__ deg, int* __restrict__ offs,
                                                   int* __restrict__ cursor, int n) {
    __shared__ int wsum[4];
    int t = threadIdx.x;
    int chunk = (n + 255) / 256;
    int lo = t * chunk, hi = lo + chunk;
    if (hi > n) hi = n;
    if (lo > n) lo = n;
    int s = 0;
    for (int i = lo; i < hi; i++) s += deg[i];
    // inclusive wave scan of s
    int v = s;
#pragma unroll
    for (int d = 1; d < 64; d <<= 1) {
        int nb = __shfl_up(v, d, 64);
        if ((t & 63) >= d) v += nb;
    }
    if ((t & 63) == 63) wsum[t >> 6] = v;
    __syncthreads();
    int woff = 0;
#pragma unroll
    for (int w = 0; w < 4; w++)
        if (w < (t >> 6)) woff += wsum[w];
    int run = woff + v - s;  // exclusive prefix for this thread's chunk
    for (int i = lo; i < hi; i++) {
        offs[i] = run;
        cursor[i] = run;
        run += deg[i];
    }
    if (t == 255) offs[n] = run;  // thread 255's chunk is clamped at n -> run == total
}

// ---------------- fused: emb GEMM -> 8KB LDS -> fc1 GEMM + elr1 (16-row tiles); fill tail ----------------
// GEMM blocks (< NB): 16 output rows, 4 waves each own 4 of the 16 column-tiles (ct).
// Tail blocks (>= NB): CSR fill (atomic cursor scatter), overlapped with GEMM compute.
__global__ __launch_bounds__(256) void fused_emb_fc1(const u16* __restrict__ Ah, const u16* __restrict__ Bemb,
                                                     const float* __restrict__ bemb, const u16* __restrict__ Bfc1,
                                                     const float* __restrict__ al, const float* __restrict__ ar,
                                                     u16* __restrict__ hh, u16* __restrict__ feat1,
                                                     u16* __restrict__ el, u16* __restrict__ er,
                                                     const int* __restrict__ src, const int* __restrict__ dstv,
                                                     int* __restrict__ cursor, int* __restrict__ srcs,
                                                     int M, int NB, int E, int N) {
    if ((int)blockIdx.x >= NB) {  // ---- CSR fill tail (block-uniform branch; barriers below stay uniform) ----
        int i = ((int)blockIdx.x - NB) * 256 + (int)threadIdx.x;
        if (i < E) {
            unsigned d = (unsigned)dstv[i];
            if (d < (unsigned)N) {
                int p = atomicAdd(&cursor[d], 1);
                if ((unsigned)p < (unsigned)E) srcs[p] = src[i];
            }
        }
        return;
    }
    __shared__ u16 tile[16 * 256];  // 8 KB, reused: swizzled hh tile, then plain feat1 tile
    const int t = threadIdx.x;
    const int lane = t & 63, w = t >> 6;
    const int rb = (int)blockIdx.x * 16;
    const int m = lane & 15, q = lane >> 4;
    const int arow = rb + m;

    // ---- stage 1: emb GEMM (K=128), this wave's ct = w*4 .. w*4+3 ----
    short8 a0[4];
#pragma unroll
    for (int kb = 0; kb < 4; kb++) {
        if (arow < M) a0[kb] = *(const short8*)(Ah + (size_t)arow * 128 + kb * 32 + q * 8);
        else a0[kb] = (short8){0, 0, 0, 0, 0, 0, 0, 0};
    }
    const short8* B8 = (const short8*)Bemb;
#pragma unroll
    for (int ct2 = 0; ct2 < 4; ct2++) {
        const int ct = w * 4 + ct2;
        f32x4 acc = {0.f, 0.f, 0.f, 0.f};
#pragma unroll
        for (int kb = 0; kb < 4; kb++)
            acc = __builtin_amdgcn_mfma_f32_16x16x32_bf16(a0[kb], B8[(ct * 4 + kb) * 64 + lane], acc, 0, 0, 0);
        float bv = bemb[ct * 16 + m];
#pragma unroll
        for (int r = 0; r < 4; r++) {
            int rl = q * 4 + r;
            int ro = rb + rl;
            u16 hv = 0;
            if (ro < M) {
                hv = f2bf(acc[r] + bv);
                hh[(size_t)ro * 256 + ct * 16 + m] = hv;
            }
            int byte = rl * 512 + (ct * 16 + m) * 2;
            tile[(byte ^ ((rl & 7) << 4)) >> 1] = hv;  // XOR-swizzle: b128 reads below are ~2-way (free)
        }
    }
    __syncthreads();

    // ---- stage 2: fc1 A-fragments straight from LDS (no global hh re-read) ----
    short8 af[8];
    {
        int rl = m;
#pragma unroll
        for (int kb = 0; kb < 8; kb++) {
            int byte = rl * 512 + kb * 64 + q * 16;
            af[kb] = *(const short8*)(tile + ((byte ^ ((rl & 7) << 4)) >> 1));
        }
    }
    __syncthreads();  // all af reads drained before tile is overwritten as feat1 tile

    const short8* Bf = (const short8*)Bfc1;
#pragma unroll
    for (int ct2 = 0; ct2 < 4; ct2++) {
        const int ct = w * 4 + ct2;
        f32x4 acc = {0.f, 0.f, 0.f, 0.f};
#pragma unroll
        for (int kb = 0; kb < 8; kb++)
            acc = __builtin_amdgcn_mfma_f32_16x16x32_bf16(af[kb], Bf[(ct * 8 + kb) * 64 + lane], acc, 0, 0, 0);
#pragma unroll
        for (int r = 0; r < 4; r++) {
            int rl = q * 4 + r;
            int ro = rb + rl;
            u16 v = 0;
            if (ro < M) {
                v = f2bf(acc[r]);
                feat1[(size_t)ro * 256 + ct * 16 + m] = v;
            }
            tile[rl * 256 + ct * 16 + m] = v;  // plain layout for elr epilogue
        }
    }
    __syncthreads();

    // ---- stage 3: el/er epilogue from feat1 tile (16 nodes x 8 heads = 128 tasks) ----
    if (t < 128) {
        int nl = t >> 3, h2 = t & 7;
        int node = rb + nl;
        if (node < M) {
            float a_ = 0.f, b_ = 0.f;
#pragma unroll
            for (int d = 0; d < 32; d++) {
                float fv = bf2f(tile[nl * 256 + h2 * 32 + d]);
                a_ += fv * al[h2 * 32 + d];
                b_ += fv * ar[h2 * 32 + d];
            }
            el[node * 8 + h2] = f2bf(a_);
            er[node * 8 + h2] = f2bf(b_);
        }
    }
}

// exp(leaky_relu(l)); logits O(0.1), max-subtraction unnecessary (identical ratios)
__device__ __forceinline__ float edgew(float l) {
    l = (l > 0.f) ? l : 0.2f * l;
    l = fminf(fmaxf(l, -30.f), 30.f);
    return __expf(l);
}

// ---------------- agg1: fused edge weights (NO stats fusion) ----------------
__global__ __launch_bounds__(256) void agg1_fused(const u16* __restrict__ feat, const u16* __restrict__ el,
                                                  const u16* __restrict__ er, const int* __restrict__ offs,
                                                  const int* __restrict__ srcs, u16* __restrict__ rst, int N, int E) {
    const int node = blockIdx.x * 4 + (threadIdx.x >> 6);
    const int lane = threadIdx.x & 63;
    if (node >= N) return;
    const int h = lane >> 3;
    int beg = offs[node], end = offs[node + 1];
    if (beg < 0) beg = 0;
    if (end > E) end = E;
    float ern = bf2f(er[node * 8 + h]);
    float ax = 0.f, ay = 0.f, az = 0.f, aw = 0.f, sw = 0.f;
    int j = beg;
    int end4 = beg + ((end - beg) & ~3);
    for (; j < end4; j += 4) {  // 4-deep software pipeline
        int s0 = srcs[j], s1 = srcs[j + 1], s2 = srcs[j + 2], s3 = srcs[j + 3];
        unsigned c0 = (unsigned)s0 < (unsigned)N, c1 = (unsigned)s1 < (unsigned)N;
        unsigned c2 = (unsigned)s2 < (unsigned)N, c3 = (unsigned)s3 < (unsigned)N;
        s0 = c0 ? s0 : 0; s1 = c1 ? s1 : 0; s2 = c2 ? s2 : 0; s3 = c3 ? s3 : 0;
        u16 e0 = el[s0 * 8 + h], e1 = el[s1 * 8 + h], e2 = el[s2 * 8 + h], e3 = el[s3 * 8 + h];
        ushort4 f0 = *(const ushort4*)(feat + (size_t)s0 * 256 + lane * 4);
        ushort4 f1 = *(const ushort4*)(feat + (size_t)s1 * 256 + lane * 4);
        ushort4 f2 = *(const ushort4*)(feat + (size_t)s2 * 256 + lane * 4);
        ushort4 f3 = *(const ushort4*)(feat + (size_t)s3 * 256 + lane * 4);
        float w0 = c0 ? edgew(bf2f(e0) + ern) : 0.f;
        float w1 = c1 ? edgew(bf2f(e1) + ern) : 0.f;
        float w2 = c2 ? edgew(bf2f(e2) + ern) : 0.f;
        float w3 = c3 ? edgew(bf2f(e3) + ern) : 0.f;
        sw += w0 + w1 + w2 + w3;
        ax += w0 * bf2f(f0.x) + w1 * bf2f(f1.x) + w2 * bf2f(f2.x) + w3 * bf2f(f3.x);
        ay += w0 * bf2f(f0.y) + w1 * bf2f(f1.y) + w2 * bf2f(f2.y) + w3 * bf2f(f3.y);
        az += w0 * bf2f(f0.z) + w1 * bf2f(f1.z) + w2 * bf2f(f2.z) + w3 * bf2f(f3.z);
        aw += w0 * bf2f(f0.w) + w1 * bf2f(f1.w) + w2 * bf2f(f2.w) + w3 * bf2f(f3.w);
    }
    for (; j < end; j++) {
        int s = srcs[j];
        if ((unsigned)s >= (unsigned)N) continue;
        float wv = edgew(bf2f(el[s * 8 + h]) + ern);
        ushort4 f4 = *(const ushort4*)(feat + (size_t)s * 256 + lane * 4);
        sw += wv;
        ax += wv * bf2f(f4.x);
        ay += wv * bf2f(f4.y);
        az += wv * bf2f(f4.z);
        aw += wv * bf2f(f4.w);
    }
    float inv = 1.f / (sw + 1e-16f);
    ushort4 o;
    o.x = f2bf(ax * inv); o.y = f2bf(ay * inv); o.z = f2bf(az * inv); o.w = f2bf(aw * inv);
    *(ushort4*)(rst + (size_t)node * 256 + lane * 4) = o;
}

// ---------------- bn stats, separate low-contention kernels ----------------
__global__ __launch_bounds__(256) void bn_stats256(const u16* __restrict__ X, float* __restrict__ stats,
                                                   int rows, int RPB) {
    int t = threadIdx.x;
    int rbeg = blockIdx.x * RPB;
    int rend = rbeg + RPB;
    if (rend > rows) rend = rows;
    float s = 0.f, s2 = 0.f;
    for (int r = rbeg; r < rend; r++) {
        float x = bf2f(X[(long)r * 256 + t]);
        s += x;
        s2 += x * x;
    }
    atomicAdd(&stats[t], s);
    atomicAdd(&stats[256 + t], s2);
}

__global__ __launch_bounds__(256) void bn_stats32(const float* __restrict__ X, float* __restrict__ stats,
                                                  int rows, int RPB) {
    __shared__ float ss[256], ss2[256];
    int t = threadIdx.x, c = t & 31, rs = t >> 5;
    int rbeg = blockIdx.x * RPB;
    int rend = rbeg + RPB;
    if (rend > rows) rend = rows;
    float s = 0.f, s2 = 0.f;
    for (int r = rbeg + rs; r < rend; r += 8) {
        float x = X[(long)r * 32 + c];
        s += x;
        s2 += x * x;
    }
    ss[t] = s;
    ss2[t] = s2;
    __syncthreads();
    if (t < 32) {
        for (int j = 32; j < 256; j += 32) { s += ss[t + j]; s2 += ss2[t + j]; }
        atomicAdd(&stats[c], s);
        atomicAdd(&stats[32 + c], s2);
    }
}

// ---------------- fc2 GEMM, 16-row tiles, (ct x K-half) wave split + LDS reduce ----------------
// Block = 16 rows (625 blocks). Wave w: ct = w&1 (of 2 column-tiles), kh = w>>1 (K half).
// Waves 2,3 write f32x4 partials to LDS; waves 0,1 reduce, store feat2 + elr tile.
// bn_apply1(+residual+elu) fused into the A-fragment load (per wave's K-slice).
__global__ __launch_bounds__(256) void gemm_fc2_fused(const u16* __restrict__ rst, const u16* __restrict__ hh,
                                                      const float* __restrict__ stats, const float* __restrict__ g,
                                                      const float* __restrict__ b, const u16* __restrict__ Bsw,
                                                      const float* __restrict__ al2, const float* __restrict__ ar2,
                                                      float* __restrict__ feat2, float* __restrict__ el2,
                                                      float* __restrict__ er2, int M, float invN) {
    __shared__ float sc[256], sh[256];
    __shared__ float red[2][256];   // partial acc from waves 2,3 (per ct: 64 lanes x f32x4)
    __shared__ float tile[16][32];
    const int t = threadIdx.x;
    {
        float mu = stats[t] * invN;
        float var = fmaxf(stats[256 + t] * invN - mu * mu, 0.f);
        float s = g[t] * rsqrtf(var + 1e-5f);
        sc[t] = s;
        sh[t] = b[t] - mu * s;
    }
    __syncthreads();
    const int lane = t & 63, w = t >> 6;
    const int ct = w & 1, kh = w >> 1;
    const int rb = (int)blockIdx.x * 16;
    const int m = lane & 15, q = lane >> 4;
    const int row = rb + m;
    short8 a[4];
#pragma unroll
    for (int j = 0; j < 4; j++) {
        if (row < M) {
            int k0 = (kh * 4 + j) * 32 + q * 8;
            ushort4 r01 = *(const ushort4*)(rst + (size_t)row * 256 + k0);
            ushort4 r23 = *(const ushort4*)(rst + (size_t)row * 256 + k0 + 4);
            ushort4 h01 = *(const ushort4*)(hh + (size_t)row * 256 + k0);
            ushort4 h23 = *(const ushort4*)(hh + (size_t)row * 256 + k0 + 4);
            u16 rv[8] = {r01.x, r01.y, r01.z, r01.w, r23.x, r23.y, r23.z, r23.w};
            u16 hv[8] = {h01.x, h01.y, h01.z, h01.w, h23.x, h23.y, h23.z, h23.w};
            short8 av;
#pragma unroll
            for (int jj = 0; jj < 8; jj++) {
                int c = k0 + jj;
                float y = sc[c] * bf2f(rv[jj]) + sh[c];
                y = (y > 0.f) ? y : expm1f(y);
                av[jj] = (short)f2bf(bf2f(hv[jj]) + y);
            }
            a[j] = av;
        } else a[j] = (short8){0, 0, 0, 0, 0, 0, 0, 0};
    }
    const short8* B8 = (const short8*)Bsw;
    f32x4 acc = {0.f, 0.f, 0.f, 0.f};
#pragma unroll
    for (int j = 0; j < 4; j++)
        acc = __builtin_amdgcn_mfma_f32_16x16x32_bf16(a[j], B8[(ct * 8 + kh * 4 + j) * 64 + lane], acc, 0, 0, 0);
    if (kh == 1) *(f32x4*)&red[ct][lane * 4] = acc;
    __syncthreads();
    if (kh == 0) {
        f32x4 p = *(const f32x4*)&red[ct][lane * 4];
#pragma unroll
        for (int r = 0; r < 4; r++) {
            int rl = q * 4 + r;
            int ro = rb + rl;
            float v = 0.f;
            if (ro < M) {
                v = acc[r] + p[r];
                feat2[(size_t)ro * 32 + ct * 16 + m] = v;
            }
            tile[rl][ct * 16 + m] = v;
        }
    }
    __syncthreads();
    if (t < 16) {
        int node = rb + t;
        if (node < M) {
            float a_ = 0.f, b_ = 0.f;
#pragma unroll
            for (int d = 0; d < 32; d++) {
                float fv = tile[t][d];
                a_ += fv * al2[d];
                b_ += fv * ar2[d];
            }
            el2[node] = a_;
            er2[node] = b_;
        }
    }
}

// ---------------- agg2: fused edge weights, 4-deep pipeline (R19) ----------------
// Accumulation order identical to the serial loop: per edge, sw += w; acc += w*f.
// Clamped/out-of-range edges contribute w = 0.0f (adds +0.0f, bit-neutral).
__global__ __launch_bounds__(256) void agg2_fused(const float* __restrict__ feat, const float* __restrict__ el,
                                                  const float* __restrict__ er, const int* __restrict__ offs,
                                                  const int* __restrict__ srcs, float* __restrict__ rst,
                                                  int N, int E) {
    const int t = threadIdx.x;
    const int node = blockIdx.x * 8 + (t >> 5);
    const int d = t & 31;
    if (node >= N) return;
    int beg = offs[node], end = offs[node + 1];
    if (beg < 0) beg = 0;
    if (end > E) end = E;
    float ern = er[node];
    float acc = 0.f, sw = 0.f;
    int j = beg;
    int end4 = beg + ((end - beg) & ~3);
    for (; j < end4; j += 4) {  // 4-deep software pipeline
        int s0 = srcs[j], s1 = srcs[j + 1], s2 = srcs[j + 2], s3 = srcs[j + 3];
        unsigned c0 = (unsigned)s0 < (unsigned)N, c1 = (unsigned)s1 < (unsigned)N;
        unsigned c2 = (unsigned)s2 < (unsigned)N, c3 = (unsigned)s3 < (unsigned)N;
        s0 = c0 ? s0 : 0; s1 = c1 ? s1 : 0; s2 = c2 ? s2 : 0; s3 = c3 ? s3 : 0;
        float e0 = el[s0], e1 = el[s1], e2 = el[s2], e3 = el[s3];
        float f0 = feat[(size_t)s0 * 32 + d];
        float f1 = feat[(size_t)s1 * 32 + d];
        float f2 = feat[(size_t)s2 * 32 + d];
        float f3 = feat[(size_t)s3 * 32 + d];
        float w0 = c0 ? edgew(e0 + ern) : 0.f;
        float w1 = c1 ? edgew(e1 + ern) : 0.f;
        float w2 = c2 ? edgew(e2 + ern) : 0.f;
        float w3 = c3 ? edgew(e3 + ern) : 0.f;
        sw += w0; acc += w0 * f0;
        sw += w1; acc += w1 * f1;
        sw += w2; acc += w2 * f2;
        sw += w3; acc += w3 * f3;
    }
    for (; j < end; j++) {
        int s = srcs[j];
        if ((unsigned)s >= (unsigned)N) continue;
        float wv = edgew(el[s] + ern);
        sw += wv;
        acc += wv * feat[(size_t)s * 32 + d];
    }
    rst[(size_t)node * 32 + d] = acc / (sw + 1e-16f);
}

// ---------------- final bn + elu -> f32 out ----------------
__global__ __launch_bounds__(256) void bn_apply2(const float* __restrict__ rst, const float* __restrict__ stats,
                                                 const float* __restrict__ g, const float* __restrict__ b,
                                                 float* __restrict__ out, int total, float invN) {
    int idx = blockIdx.x * 256 + threadIdx.x;
    if (idx >= total) return;
    int c = idx & 31;
    float mu = stats[c] * invN;
    float var = fmaxf(stats[32 + c] * invN - mu * mu, 0.f);
    float y = g[c] * (rst[idx] - mu) * rsqrtf(var + 1e-5f) + b[c];
    y = (y > 0.f) ? y : expm1f(y);
    out[idx] = y;
}

extern "C" void kernel_launch(void* const* d_in, const int* in_sizes, int n_in, void* d_out, int out_size, void* d_ws,
                              size_t ws_size, hipStream_t stream) {
    const int N = out_size / ODIM;
    const int E = in_sizes[2];

    const int* src = (const int*)d_in[2];
    const int* dst = (const int*)d_in[3];
    const float* in_h = (const float*)d_in[0];
    const float* W_emb = (const float*)d_in[4];  const float* b_emb = (const float*)d_in[5];
    const float* fc1 = (const float*)d_in[18];   const float* al1 = (const float*)d_in[19];
    const float* ar1 = (const float*)d_in[20];
    const float* g1 = (const float*)d_in[21];    const float* b1 = (const float*)d_in[22];
    const float* fc2 = (const float*)d_in[23];   const float* al2 = (const float*)d_in[24];
    const float* ar2 = (const float*)d_in[25];
    const float* g2 = (const float*)d_in[26];    const float* b2 = (const float*)d_in[27];
    float* out = (float*)d_out;

    // ---- ws layout (~26 MB) ----
    char* base = (char*)d_ws;
    size_t off = 0;
    auto alloc = [&](size_t bytes) { void* p = base + off; off += (bytes + 63) & ~63ull; return p; };
    char* zb   = (char*)alloc((size_t)N * 4 + 512 * 4 + 64 * 4);
    int* deg   = (int*)zb;
    float* stats  = (float*)(zb + (size_t)N * 4);
    float* stats2 = stats + 512;
    int* offs  = (int*)alloc((size_t)(N + 1) * 4);
    int* cursor = (int*)alloc((size_t)N * 4);
    int* srcs  = (int*)alloc((size_t)E * 4);
    u16* Ah    = (u16*)alloc((size_t)N * 128 * 2);
    u16* Bemb  = (u16*)alloc((size_t)128 * 256 * 2);
    u16* Bfc1  = (u16*)alloc((size_t)256 * 256 * 2);
    u16* Bfc2  = (u16*)alloc((size_t)256 * 32 * 2);
    u16* hh    = (u16*)alloc((size_t)N * HDIM * 2);
    u16* feat1 = (u16*)alloc((size_t)N * HDIM * 2);
    u16* el1   = (u16*)alloc((size_t)N * 8 * 2);
    u16* er1   = (u16*)alloc((size_t)N * 8 * 2);
    u16* rst   = (u16*)alloc((size_t)N * HDIM * 2);
    float* feat2 = (float*)alloc((size_t)N * 32 * 4);
    float* el2 = (float*)alloc((size_t)N * 4);
    float* er2 = (float*)alloc((size_t)N * 4);
    float* rst2 = (float*)alloc((size_t)N * 32 * 4);

    const int NB16 = (N + 15) / 16;
    const int NBF = (E + 255) / 256;  // fill tail blocks

    hipMemsetAsync(zb, 0, (size_t)N * 4 + 512 * 4 + 64 * 4, stream);
    prep_kernel<<<dim3((N * 128 / 4 + 255) / 256, 5), 256, 0, stream>>>(in_h, W_emb, fc1, fc2, dst, deg,
                                                                        Ah, Bemb, Bfc1, Bfc2, N * 128 / 4, E, N);
    scan_kernel<<<1, 256, 0, stream>>>(deg, offs, cursor, N);
    fused_emb_fc1<<<NB16 + NBF, 256, 0, stream>>>(Ah, Bemb, b_emb, Bfc1, al1, ar1, hh, feat1, el1, er1,
                                                  src, dst, cursor, srcs, N, NB16, E, N);
    agg1_fused<<<(N + 3) / 4, 256, 0, stream>>>(feat1, el1, er1, offs, srcs, rst, N, E);
    bn_stats256<<<(N + 39) / 40, 256, 0, stream>>>(rst, stats, N, 40);
    gemm_fc2_fused<<<NB16, 256, 0, stream>>>(rst, hh, stats, g1, b1, Bfc2, al2, ar2, feat2, el2, er2, N, 1.f / N);
    agg2_fused<<<(N + 7) / 8, 256, 0, stream>>>(feat2, el2, er2, offs, srcs, rst2, N, E);
    bn_stats32<<<(N + 63) / 64, 256, 0, stream>>>(rst2, stats2, N, 64);
    bn_apply2<<<(N * ODIM + 255) / 256, 256, 0, stream>>>(rst2, stats2, g2, b2, out, N * ODIM, 1.f / N);
}

// Round 9
// 241.892 us; speedup vs baseline: 5.7261x; 1.0321x over previous
//
#include <hip/hip_runtime.h>
#include <hip/hip_bf16.h>
#include <math.h>

// GATNet: hh = h@W_emb+b_emb -> GAT(8 heads,32,residual) -> GAT(1 head,32) -> out f32.
// Edge-feature branch of the reference is dead code (del e_feat) -> skipped.
// R20: body shrink, structure = R19 (verified 249.7us, 10 graph nodes — dependency
// chain is fully serial so dispatch count is at its floor). Changes:
// (a) agg1: wave split into two 32-lane halves with independent even/odd edge streams
//     (8 edges in flight vs 4) + 16B short8 feat loads (was 8B ushort4). Halves
//     combined via shfl_xor(32) — reassociates column sums (f32 ~1e-7, bf16-safe).
// (b) bn_stats256: short8 16B reads, 8 rows/iter (40->5 loop steps), LDS col-reduce,
//     same 512-atomic tail (contention level known-good).
// (c) bn_apply2: float4 (bit-identical math).
// prep/scan/fused_emb_fc1/fc2/agg2/bn_stats32 byte-identical to R19.

#define HDIM 256
#define NHEADS 8
#define ODIM 32

typedef unsigned short u16;
typedef __attribute__((ext_vector_type(8))) short short8;
typedef __attribute__((ext_vector_type(4))) float f32x4;

__device__ __forceinline__ float bf2f(u16 u) { return __uint_as_float(((unsigned)u) << 16); }
__device__ __forceinline__ u16 f2bf(float f) {
    unsigned x = __float_as_uint(f);
    return (u16)((x + 0x7FFFu + ((x >> 16) & 1u)) >> 16);  // RNE
}

// ---------------- prep: batched cvt + B swizzles + deg ----------------
__global__ __launch_bounds__(256) void prep_kernel(const float* __restrict__ in_h, const float* __restrict__ W_emb,
                                                   const float* __restrict__ fc1, const float* __restrict__ fc2,
                                                   const int* __restrict__ dstv, int* __restrict__ deg,
                                                   u16* __restrict__ Ah, u16* __restrict__ Bemb,
                                                   u16* __restrict__ Bfc1, u16* __restrict__ Bfc2,
                                                   int n4, int E, int N) {
    int job = blockIdx.y;
    int idx = blockIdx.x * 256 + threadIdx.x;
    if (job == 0) {
        if (idx >= n4) return;
        float4 v = ((const float4*)in_h)[idx];
        ushort4 o = {f2bf(v.x), f2bf(v.y), f2bf(v.z), f2bf(v.w)};
        ((ushort4*)Ah)[idx] = o;
        return;
    }
    if (job == 4) {  // degree count (independent of cvt jobs; deg pre-zeroed by memset)
        if (idx < E) {
            unsigned d = (unsigned)dstv[idx];
            if (d < (unsigned)N) atomicAdd(&deg[d], 1);
        }
        return;
    }
    const float* B;
    u16* O;
    int K, NC;
    if (job == 1) { B = W_emb; O = Bemb; K = 128; NC = 256; }
    else if (job == 2) { B = fc1; O = Bfc1; K = 256; NC = 256; }
    else { B = fc2; O = Bfc2; K = 256; NC = 32; }
    int KB = K / 32;
    int TOT = (NC / 16) * KB * 64;
    if (idx >= TOT) return;
    int lane = idx & 63;
    int kb = (idx >> 6) % KB;
    int ct = (idx >> 6) / KB;
    int n = ct * 16 + (lane & 15);
    int k0 = kb * 32 + (lane >> 4) * 8;
    u16* dst = O + (size_t)idx * 8;
#pragma unroll
    for (int j = 0; j < 8; j++) dst[j] = f2bf(B[(size_t)(k0 + j) * NC + n]);
}

// ---------------- CSR scan (wave-parallel) ----------------
__global__ __launch_bounds__(256) void scan_kernel(const int* __restrict__ deg, int* __restrict__ offs,
                                                   int* __restrict__ cursor, int n) {
    __shared__ int wsum[4];
    int t = threadIdx.x;
    int chunk = (n + 255) / 256;
    int lo = t * chunk, hi = lo + chunk;
    if (hi > n) hi = n;
    if (lo > n) lo = n;
    int s = 0;
    for (int i = lo; i < hi; i++) s += deg[i];
    // inclusive wave scan of s
    int v = s;
#pragma unroll
    for (int d = 1; d < 64; d <<= 1) {
        int nb = __shfl_up(v, d, 64);
        if ((t & 63) >= d) v += nb;
    }
    if ((t & 63) == 63) wsum[t >> 6] = v;
    __syncthreads();
    int woff = 0;
#pragma unroll
    for (int w = 0; w < 4; w++)
        if (w < (t >> 6)) woff += wsum[w];
    int run = woff + v - s;  // exclusive prefix for this thread's chunk
    for (int i = lo; i < hi; i++) {
        offs[i] = run;
        cursor[i] = run;
        run += deg[i];
    }
    if (t == 255) offs[n] = run;  // thread 255's chunk is clamped at n -> run == total
}

// ---------------- fused: emb GEMM -> 8KB LDS -> fc1 GEMM + elr1 (16-row tiles); fill tail ----------------
__global__ __launch_bounds__(256) void fused_emb_fc1(const u16* __restrict__ Ah, const u16* __restrict__ Bemb,
                                                     const float* __restrict__ bemb, const u16* __restrict__ Bfc1,
                                                     const float* __restrict__ al, const float* __restrict__ ar,
                                                     u16* __restrict__ hh, u16* __restrict__ feat1,
                                                     u16* __restrict__ el, u16* __restrict__ er,
                                                     const int* __restrict__ src, const int* __restrict__ dstv,
                                                     int* __restrict__ cursor, int* __restrict__ srcs,
                                                     int M, int NB, int E, int N) {
    if ((int)blockIdx.x >= NB) {  // ---- CSR fill tail (block-uniform branch; barriers below stay uniform) ----
        int i = ((int)blockIdx.x - NB) * 256 + (int)threadIdx.x;
        if (i < E) {
            unsigned d = (unsigned)dstv[i];
            if (d < (unsigned)N) {
                int p = atomicAdd(&cursor[d], 1);
                if ((unsigned)p < (unsigned)E) srcs[p] = src[i];
            }
        }
        return;
    }
    __shared__ u16 tile[16 * 256];  // 8 KB, reused: swizzled hh tile, then plain feat1 tile
    const int t = threadIdx.x;
    const int lane = t & 63, w = t >> 6;
    const int rb = (int)blockIdx.x * 16;
    const int m = lane & 15, q = lane >> 4;
    const int arow = rb + m;

    // ---- stage 1: emb GEMM (K=128), this wave's ct = w*4 .. w*4+3 ----
    short8 a0[4];
#pragma unroll
    for (int kb = 0; kb < 4; kb++) {
        if (arow < M) a0[kb] = *(const short8*)(Ah + (size_t)arow * 128 + kb * 32 + q * 8);
        else a0[kb] = (short8){0, 0, 0, 0, 0, 0, 0, 0};
    }
    const short8* B8 = (const short8*)Bemb;
#pragma unroll
    for (int ct2 = 0; ct2 < 4; ct2++) {
        const int ct = w * 4 + ct2;
        f32x4 acc = {0.f, 0.f, 0.f, 0.f};
#pragma unroll
        for (int kb = 0; kb < 4; kb++)
            acc = __builtin_amdgcn_mfma_f32_16x16x32_bf16(a0[kb], B8[(ct * 4 + kb) * 64 + lane], acc, 0, 0, 0);
        float bv = bemb[ct * 16 + m];
#pragma unroll
        for (int r = 0; r < 4; r++) {
            int rl = q * 4 + r;
            int ro = rb + rl;
            u16 hv = 0;
            if (ro < M) {
                hv = f2bf(acc[r] + bv);
                hh[(size_t)ro * 256 + ct * 16 + m] = hv;
            }
            int byte = rl * 512 + (ct * 16 + m) * 2;
            tile[(byte ^ ((rl & 7) << 4)) >> 1] = hv;  // XOR-swizzle: b128 reads below are ~2-way (free)
        }
    }
    __syncthreads();

    // ---- stage 2: fc1 A-fragments straight from LDS (no global hh re-read) ----
    short8 af[8];
    {
        int rl = m;
#pragma unroll
        for (int kb = 0; kb < 8; kb++) {
            int byte = rl * 512 + kb * 64 + q * 16;
            af[kb] = *(const short8*)(tile + ((byte ^ ((rl & 7) << 4)) >> 1));
        }
    }
    __syncthreads();  // all af reads drained before tile is overwritten as feat1 tile

    const short8* Bf = (const short8*)Bfc1;
#pragma unroll
    for (int ct2 = 0; ct2 < 4; ct2++) {
        const int ct = w * 4 + ct2;
        f32x4 acc = {0.f, 0.f, 0.f, 0.f};
#pragma unroll
        for (int kb = 0; kb < 8; kb++)
            acc = __builtin_amdgcn_mfma_f32_16x16x32_bf16(af[kb], Bf[(ct * 8 + kb) * 64 + lane], acc, 0, 0, 0);
#pragma unroll
        for (int r = 0; r < 4; r++) {
            int rl = q * 4 + r;
            int ro = rb + rl;
            u16 v = 0;
            if (ro < M) {
                v = f2bf(acc[r]);
                feat1[(size_t)ro * 256 + ct * 16 + m] = v;
            }
            tile[rl * 256 + ct * 16 + m] = v;  // plain layout for elr epilogue
        }
    }
    __syncthreads();

    // ---- stage 3: el/er epilogue from feat1 tile (16 nodes x 8 heads = 128 tasks) ----
    if (t < 128) {
        int nl = t >> 3, h2 = t & 7;
        int node = rb + nl;
        if (node < M) {
            float a_ = 0.f, b_ = 0.f;
#pragma unroll
            for (int d = 0; d < 32; d++) {
                float fv = bf2f(tile[nl * 256 + h2 * 32 + d]);
                a_ += fv * al[h2 * 32 + d];
                b_ += fv * ar[h2 * 32 + d];
            }
            el[node * 8 + h2] = f2bf(a_);
            er[node * 8 + h2] = f2bf(b_);
        }
    }
}

// exp(leaky_relu(l)); logits O(0.1), max-subtraction unnecessary (identical ratios)
__device__ __forceinline__ float edgew(float l) {
    l = (l > 0.f) ? l : 0.2f * l;
    l = fminf(fmaxf(l, -30.f), 30.f);
    return __expf(l);
}

// ---------------- agg1: dual 32-lane edge streams, 16B feat loads (R20) ----------------
// Wave = 1 node. half = lane>>5 selects even/odd CSR-offset edge stream; each half runs
// its own 4-deep pipeline (8 edges in flight/wave). Lane owns 8 columns (sl*8..sl*8+7),
// head h = sl>>2 (same column->head map as R19). Halves combined via shfl_xor(32):
// column sum = (even-edge sum) + (odd-edge sum) — reassociation only.
__global__ __launch_bounds__(256) void agg1_fused(const u16* __restrict__ feat, const u16* __restrict__ el,
                                                  const u16* __restrict__ er, const int* __restrict__ offs,
                                                  const int* __restrict__ srcs, u16* __restrict__ rst, int N, int E) {
    const int node = blockIdx.x * 4 + (threadIdx.x >> 6);
    const int lane = threadIdx.x & 63;
    if (node >= N) return;
    const int half = lane >> 5;
    const int sl = lane & 31;
    const int h = sl >> 2;
    int beg = offs[node], end = offs[node + 1];
    if (beg < 0) beg = 0;
    if (end > E) end = E;
    int cnt = end - beg;
    if (cnt < 0) cnt = 0;
    float ern = bf2f(er[node * 8 + h]);
    float acc[8] = {0.f, 0.f, 0.f, 0.f, 0.f, 0.f, 0.f, 0.f};
    float sw = 0.f;
    const int myCnt = (cnt - half + 1) >> 1;  // edges in this half's stream
    const int jb = beg + half;
    int k = 0;
    int k4 = myCnt & ~3;
    for (; k < k4; k += 4) {  // 4-deep pipeline per half (8 edges in flight per wave)
        int j0 = jb + 2 * k;
        int s0 = srcs[j0], s1 = srcs[j0 + 2], s2 = srcs[j0 + 4], s3 = srcs[j0 + 6];
        unsigned c0 = (unsigned)s0 < (unsigned)N, c1 = (unsigned)s1 < (unsigned)N;
        unsigned c2 = (unsigned)s2 < (unsigned)N, c3 = (unsigned)s3 < (unsigned)N;
        s0 = c0 ? s0 : 0; s1 = c1 ? s1 : 0; s2 = c2 ? s2 : 0; s3 = c3 ? s3 : 0;
        u16 e0 = el[s0 * 8 + h], e1 = el[s1 * 8 + h], e2 = el[s2 * 8 + h], e3 = el[s3 * 8 + h];
        short8 f0 = *(const short8*)(feat + (size_t)s0 * 256 + sl * 8);
        short8 f1 = *(const short8*)(feat + (size_t)s1 * 256 + sl * 8);
        short8 f2 = *(const short8*)(feat + (size_t)s2 * 256 + sl * 8);
        short8 f3 = *(const short8*)(feat + (size_t)s3 * 256 + sl * 8);
        float w0 = c0 ? edgew(bf2f(e0) + ern) : 0.f;
        float w1 = c1 ? edgew(bf2f(e1) + ern) : 0.f;
        float w2 = c2 ? edgew(bf2f(e2) + ern) : 0.f;
        float w3 = c3 ? edgew(bf2f(e3) + ern) : 0.f;
        sw += w0 + w1 + w2 + w3;
#pragma unroll
        for (int q = 0; q < 8; q++)
            acc[q] += w0 * bf2f((u16)f0[q]) + w1 * bf2f((u16)f1[q]) + w2 * bf2f((u16)f2[q]) + w3 * bf2f((u16)f3[q]);
    }
    for (; k < myCnt; k++) {
        int j = jb + 2 * k;
        int s = srcs[j];
        if ((unsigned)s >= (unsigned)N) continue;
        float wv = edgew(bf2f(el[s * 8 + h]) + ern);
        short8 fv = *(const short8*)(feat + (size_t)s * 256 + sl * 8);
        sw += wv;
#pragma unroll
        for (int q = 0; q < 8; q++) acc[q] += wv * bf2f((u16)fv[q]);
    }
    // combine even/odd halves (lane l <-> l^32)
#pragma unroll
    for (int q = 0; q < 8; q++) acc[q] += __shfl_xor(acc[q], 32, 64);
    sw += __shfl_xor(sw, 32, 64);
    if (half == 0) {
        float inv = 1.f / (sw + 1e-16f);
        short8 o;
#pragma unroll
        for (int q = 0; q < 8; q++) o[q] = (short)f2bf(acc[q] * inv);
        *(short8*)(rst + (size_t)node * 256 + sl * 8) = o;
    }
}

// ---------------- bn stats over rst (256 cols), vectorized 16B reads (R20) ----------------
// Thread t = rg*32+cg: reads short8 of cols cg*8..cg*8+7 at rows rbeg+rg, +8, ...
// (8 rows/iter). LDS column reduce across the 8 row-groups, then 512 atomics/block
// (same contention level as R19's known-good tail).
__global__ __launch_bounds__(256) void bn_stats256(const u16* __restrict__ X, float* __restrict__ stats,
                                                   int rows, int RPB) {
    __shared__ float ps[256][8], ps2[256][8];  // 16 KB
    int t = threadIdx.x;
    int rg = t >> 5, cg = t & 31;
    int rbeg = blockIdx.x * RPB;
    int rend = rbeg + RPB;
    if (rend > rows) rend = rows;
    float s[8] = {0.f, 0.f, 0.f, 0.f, 0.f, 0.f, 0.f, 0.f};
    float s2[8] = {0.f, 0.f, 0.f, 0.f, 0.f, 0.f, 0.f, 0.f};
    for (int r = rbeg + rg; r < rend; r += 8) {
        short8 v = *(const short8*)(X + (size_t)r * 256 + cg * 8);
#pragma unroll
        for (int q = 0; q < 8; q++) {
            float x = bf2f((u16)v[q]);
            s[q] += x;
            s2[q] += x * x;
        }
    }
#pragma unroll
    for (int q = 0; q < 8; q++) { ps[t][q] = s[q]; ps2[t][q] = s2[q]; }
    __syncthreads();
    // thread t reduces column t across the 8 row-groups
    float a = 0.f, b = 0.f;
#pragma unroll
    for (int g = 0; g < 8; g++) {
        a += ps[g * 32 + (t >> 3)][t & 7];
        b += ps2[g * 32 + (t >> 3)][t & 7];
    }
    atomicAdd(&stats[t], a);
    atomicAdd(&stats[256 + t], b);
}

__global__ __launch_bounds__(256) void bn_stats32(const float* __restrict__ X, float* __restrict__ stats,
                                                  int rows, int RPB) {
    __shared__ float ss[256], ss2[256];
    int t = threadIdx.x, c = t & 31, rs = t >> 5;
    int rbeg = blockIdx.x * RPB;
    int rend = rbeg + RPB;
    if (rend > rows) rend = rows;
    float s = 0.f, s2 = 0.f;
    for (int r = rbeg + rs; r < rend; r += 8) {
        float x = X[(long)r * 32 + c];
        s += x;
        s2 += x * x;
    }
    ss[t] = s;
    ss2[t] = s2;
    __syncthreads();
    if (t < 32) {
        for (int j = 32; j < 256; j += 32) { s += ss[t + j]; s2 += ss2[t + j]; }
        atomicAdd(&stats[c], s);
        atomicAdd(&stats[32 + c], s2);
    }
}

// ---------------- fc2 GEMM, 16-row tiles, (ct x K-half) wave split + LDS reduce ----------------
__global__ __launch_bounds__(256) void gemm_fc2_fused(const u16* __restrict__ rst, const u16* __restrict__ hh,
                                                      const float* __restrict__ stats, const float* __restrict__ g,
                                                      const float* __restrict__ b, const u16* __restrict__ Bsw,
                                                      const float* __restrict__ al2, const float* __restrict__ ar2,
                                                      float* __restrict__ feat2, float* __restrict__ el2,
                                                      float* __restrict__ er2, int M, float invN) {
    __shared__ float sc[256], sh[256];
    __shared__ float red[2][256];   // partial acc from waves 2,3 (per ct: 64 lanes x f32x4)
    __shared__ float tile[16][32];
    const int t = threadIdx.x;
    {
        float mu = stats[t] * invN;
        float var = fmaxf(stats[256 + t] * invN - mu * mu, 0.f);
        float s = g[t] * rsqrtf(var + 1e-5f);
        sc[t] = s;
        sh[t] = b[t] - mu * s;
    }
    __syncthreads();
    const int lane = t & 63, w = t >> 6;
    const int ct = w & 1, kh = w >> 1;
    const int rb = (int)blockIdx.x * 16;
    const int m = lane & 15, q = lane >> 4;
    const int row = rb + m;
    short8 a[4];
#pragma unroll
    for (int j = 0; j < 4; j++) {
        if (row < M) {
            int k0 = (kh * 4 + j) * 32 + q * 8;
            ushort4 r01 = *(const ushort4*)(rst + (size_t)row * 256 + k0);
            ushort4 r23 = *(const ushort4*)(rst + (size_t)row * 256 + k0 + 4);
            ushort4 h01 = *(const ushort4*)(hh + (size_t)row * 256 + k0);
            ushort4 h23 = *(const ushort4*)(hh + (size_t)row * 256 + k0 + 4);
            u16 rv[8] = {r01.x, r01.y, r01.z, r01.w, r23.x, r23.y, r23.z, r23.w};
            u16 hv[8] = {h01.x, h01.y, h01.z, h01.w, h23.x, h23.y, h23.z, h23.w};
            short8 av;
#pragma unroll
            for (int jj = 0; jj < 8; jj++) {
                int c = k0 + jj;
                float y = sc[c] * bf2f(rv[jj]) + sh[c];
                y = (y > 0.f) ? y : expm1f(y);
                av[jj] = (short)f2bf(bf2f(hv[jj]) + y);
            }
            a[j] = av;
        } else a[j] = (short8){0, 0, 0, 0, 0, 0, 0, 0};
    }
    const short8* B8 = (const short8*)Bsw;
    f32x4 acc = {0.f, 0.f, 0.f, 0.f};
#pragma unroll
    for (int j = 0; j < 4; j++)
        acc = __builtin_amdgcn_mfma_f32_16x16x32_bf16(a[j], B8[(ct * 8 + kh * 4 + j) * 64 + lane], acc, 0, 0, 0);
    if (kh == 1) *(f32x4*)&red[ct][lane * 4] = acc;
    __syncthreads();
    if (kh == 0) {
        f32x4 p = *(const f32x4*)&red[ct][lane * 4];
#pragma unroll
        for (int r = 0; r < 4; r++) {
            int rl = q * 4 + r;
            int ro = rb + rl;
            float v = 0.f;
            if (ro < M) {
                v = acc[r] + p[r];
                feat2[(size_t)ro * 32 + ct * 16 + m] = v;
            }
            tile[rl][ct * 16 + m] = v;
        }
    }
    __syncthreads();
    if (t < 16) {
        int node = rb + t;
        if (node < M) {
            float a_ = 0.f, b_ = 0.f;
#pragma unroll
            for (int d = 0; d < 32; d++) {
                float fv = tile[t][d];
                a_ += fv * al2[d];
                b_ += fv * ar2[d];
            }
            el2[node] = a_;
            er2[node] = b_;
        }
    }
}

// ---------------- agg2: fused edge weights, 4-deep pipeline ----------------
__global__ __launch_bounds__(256) void agg2_fused(const float* __restrict__ feat, const float* __restrict__ el,
                                                  const float* __restrict__ er, const int* __restrict__ offs,
                                                  const int* __restrict__ srcs, float* __restrict__ rst,
                                                  int N, int E) {
    const int t = threadIdx.x;
    const int node = blockIdx.x * 8 + (t >> 5);
    const int d = t & 31;
    if (node >= N) return;
    int beg = offs[node], end = offs[node + 1];
    if (beg < 0) beg = 0;
    if (end > E) end = E;
    float ern = er[node];
    float acc = 0.f, sw = 0.f;
    int j = beg;
    int end4 = beg + ((end - beg) & ~3);
    for (; j < end4; j += 4) {  // 4-deep software pipeline
        int s0 = srcs[j], s1 = srcs[j + 1], s2 = srcs[j + 2], s3 = srcs[j + 3];
        unsigned c0 = (unsigned)s0 < (unsigned)N, c1 = (unsigned)s1 < (unsigned)N;
        unsigned c2 = (unsigned)s2 < (unsigned)N, c3 = (unsigned)s3 < (unsigned)N;
        s0 = c0 ? s0 : 0; s1 = c1 ? s1 : 0; s2 = c2 ? s2 : 0; s3 = c3 ? s3 : 0;
        float e0 = el[s0], e1 = el[s1], e2 = el[s2], e3 = el[s3];
        float f0 = feat[(size_t)s0 * 32 + d];
        float f1 = feat[(size_t)s1 * 32 + d];
        float f2 = feat[(size_t)s2 * 32 + d];
        float f3 = feat[(size_t)s3 * 32 + d];
        float w0 = c0 ? edgew(e0 + ern) : 0.f;
        float w1 = c1 ? edgew(e1 + ern) : 0.f;
        float w2 = c2 ? edgew(e2 + ern) : 0.f;
        float w3 = c3 ? edgew(e3 + ern) : 0.f;
        sw += w0; acc += w0 * f0;
        sw += w1; acc += w1 * f1;
        sw += w2; acc += w2 * f2;
        sw += w3; acc += w3 * f3;
    }
    for (; j < end; j++) {
        int s = srcs[j];
        if ((unsigned)s >= (unsigned)N) continue;
        float wv = edgew(el[s] + ern);
        sw += wv;
        acc += wv * feat[(size_t)s * 32 + d];
    }
    rst[(size_t)node * 32 + d] = acc / (sw + 1e-16f);
}

// ---------------- final bn + elu -> f32 out (float4, bit-identical math) ----------------
__global__ __launch_bounds__(256) void bn_apply2(const float* __restrict__ rst, const float* __restrict__ stats,
                                                 const float* __restrict__ g, const float* __restrict__ b,
                                                 float* __restrict__ out, int total4, float invN) {
    int idx = blockIdx.x * 256 + threadIdx.x;
    if (idx >= total4) return;
    float4 v = ((const float4*)rst)[idx];
    int c0 = (idx * 4) & 31;
    float r[4] = {v.x, v.y, v.z, v.w};
#pragma unroll
    for (int j = 0; j < 4; j++) {
        int c = c0 + j;
        float mu = stats[c] * invN;
        float var = fmaxf(stats[32 + c] * invN - mu * mu, 0.f);
        float y = g[c] * (r[j] - mu) * rsqrtf(var + 1e-5f) + b[c];
        r[j] = (y > 0.f) ? y : expm1f(y);
    }
    float4 o = {r[0], r[1], r[2], r[3]};
    ((float4*)out)[idx] = o;
}

extern "C" void kernel_launch(void* const* d_in, const int* in_sizes, int n_in, void* d_out, int out_size, void* d_ws,
                              size_t ws_size, hipStream_t stream) {
    const int N = out_size / ODIM;
    const int E = in_sizes[2];

    const int* src = (const int*)d_in[2];
    const int* dst = (const int*)d_in[3];
    const float* in_h = (const float*)d_in[0];
    const float* W_emb = (const float*)d_in[4];  const float* b_emb = (const float*)d_in[5];
    const float* fc1 = (const float*)d_in[18];   const float* al1 = (const float*)d_in[19];
    const float* ar1 = (const float*)d_in[20];
    const float* g1 = (const float*)d_in[21];    const float* b1 = (const float*)d_in[22];
    const float* fc2 = (const float*)d_in[23];   const float* al2 = (const float*)d_in[24];
    const float* ar2 = (const float*)d_in[25];
    const float* g2 = (const float*)d_in[26];    const float* b2 = (const float*)d_in[27];
    float* out = (float*)d_out;

    // ---- ws layout (~26 MB) ----
    char* base = (char*)d_ws;
    size_t off = 0;
    auto alloc = [&](size_t bytes) { void* p = base + off; off += (bytes + 63) & ~63ull; return p; };
    char* zb   = (char*)alloc((size_t)N * 4 + 512 * 4 + 64 * 4);
    int* deg   = (int*)zb;
    float* stats  = (float*)(zb + (size_t)N * 4);
    float* stats2 = stats + 512;
    int* offs  = (int*)alloc((size_t)(N + 1) * 4);
    int* cursor = (int*)alloc((size_t)N * 4);
    int* srcs  = (int*)alloc((size_t)E * 4);
    u16* Ah    = (u16*)alloc((size_t)N * 128 * 2);
    u16* Bemb  = (u16*)alloc((size_t)128 * 256 * 2);
    u16* Bfc1  = (u16*)alloc((size_t)256 * 256 * 2);
    u16* Bfc2  = (u16*)alloc((size_t)256 * 32 * 2);
    u16* hh    = (u16*)alloc((size_t)N * HDIM * 2);
    u16* feat1 = (u16*)alloc((size_t)N * HDIM * 2);
    u16* el1   = (u16*)alloc((size_t)N * 8 * 2);
    u16* er1   = (u16*)alloc((size_t)N * 8 * 2);
    u16* rst   = (u16*)alloc((size_t)N * HDIM * 2);
    float* feat2 = (float*)alloc((size_t)N * 32 * 4);
    float* el2 = (float*)alloc((size_t)N * 4);
    float* er2 = (float*)alloc((size_t)N * 4);
    float* rst2 = (float*)alloc((size_t)N * 32 * 4);

    const int NB16 = (N + 15) / 16;
    const int NBF = (E + 255) / 256;  // fill tail blocks

    hipMemsetAsync(zb, 0, (size_t)N * 4 + 512 * 4 + 64 * 4, stream);
    prep_kernel<<<dim3((N * 128 / 4 + 255) / 256, 5), 256, 0, stream>>>(in_h, W_emb, fc1, fc2, dst, deg,
                                                                        Ah, Bemb, Bfc1, Bfc2, N * 128 / 4, E, N);
    scan_kernel<<<1, 256, 0, stream>>>(deg, offs, cursor, N);
    fused_emb_fc1<<<NB16 + NBF, 256, 0, stream>>>(Ah, Bemb, b_emb, Bfc1, al1, ar1, hh, feat1, el1, er1,
                                                  src, dst, cursor, srcs, N, NB16, E, N);
    agg1_fused<<<(N + 3) / 4, 256, 0, stream>>>(feat1, el1, er1, offs, srcs, rst, N, E);
    bn_stats256<<<(N + 39) / 40, 256, 0, stream>>>(rst, stats, N, 40);
    gemm_fc2_fused<<<NB16, 256, 0, stream>>>(rst, hh, stats, g1, b1, Bfc2, al2, ar2, feat2, el2, er2, N, 1.f / N);
    agg2_fused<<<(N + 7) / 8, 256, 0, stream>>>(feat2, el2, er2, offs, srcs, rst2, N, E);
    bn_stats32<<<(N + 63) / 64, 256, 0, stream>>>(rst2, stats2, N, 64);
    bn_apply2<<<(N * 8 + 255) / 256, 256, 0, stream>>>(rst2, stats2, g2, b2, out, N * 8, 1.f / N);
}

// Round 10
// 231.750 us; speedup vs baseline: 5.9767x; 1.0438x over previous
//
#include <hip/hip_runtime.h>
#include <hip/hip_bf16.h>
#include <math.h>

// GATNet: hh = h@W_emb+b_emb -> GAT(8 heads,32,residual) -> GAT(1 head,32) -> out f32.
// Edge-feature branch of the reference is dead code (del e_feat) -> skipped.
// R21: dispatch-count 10 -> 8 via SHARDED stats fusion (the safe version of R10's
// failed direct-atomic fusion). (a) agg1 block-reduces its 4 nodes' bf16-rounded
// outputs and atomicAdds per-column partials into stats_sh[bid&63][512] (39 RMWs per
// address vs R10's contended 2500); fc2 prologue reduces the 64 shards. (b) agg2
// likewise into stats2_sh[bid&31][64]; bn_apply2 prologue reduces 32 shards.
// bn_stats256/bn_stats32 dispatches deleted. Stats = same bf16-rounded values,
// different f32 summation order (reassociation only, ~1e-7).
// prep/scan/fused_emb_fc1/fc2-GEMM/agg cores byte-identical to R20.

#define HDIM 256
#define NHEADS 8
#define ODIM 32

typedef unsigned short u16;
typedef __attribute__((ext_vector_type(8))) short short8;
typedef __attribute__((ext_vector_type(4))) float f32x4;

__device__ __forceinline__ float bf2f(u16 u) { return __uint_as_float(((unsigned)u) << 16); }
__device__ __forceinline__ u16 f2bf(float f) {
    unsigned x = __float_as_uint(f);
    return (u16)((x + 0x7FFFu + ((x >> 16) & 1u)) >> 16);  // RNE
}

// ---------------- prep: batched cvt + B swizzles + deg ----------------
__global__ __launch_bounds__(256) void prep_kernel(const float* __restrict__ in_h, const float* __restrict__ W_emb,
                                                   const float* __restrict__ fc1, const float* __restrict__ fc2,
                                                   const int* __restrict__ dstv, int* __restrict__ deg,
                                                   u16* __restrict__ Ah, u16* __restrict__ Bemb,
                                                   u16* __restrict__ Bfc1, u16* __restrict__ Bfc2,
                                                   int n4, int E, int N) {
    int job = blockIdx.y;
    int idx = blockIdx.x * 256 + threadIdx.x;
    if (job == 0) {
        if (idx >= n4) return;
        float4 v = ((const float4*)in_h)[idx];
        ushort4 o = {f2bf(v.x), f2bf(v.y), f2bf(v.z), f2bf(v.w)};
        ((ushort4*)Ah)[idx] = o;
        return;
    }
    if (job == 4) {  // degree count (independent of cvt jobs; deg pre-zeroed by memset)
        if (idx < E) {
            unsigned d = (unsigned)dstv[idx];
            if (d < (unsigned)N) atomicAdd(&deg[d], 1);
        }
        return;
    }
    const float* B;
    u16* O;
    int K, NC;
    if (job == 1) { B = W_emb; O = Bemb; K = 128; NC = 256; }
    else if (job == 2) { B = fc1; O = Bfc1; K = 256; NC = 256; }
    else { B = fc2; O = Bfc2; K = 256; NC = 32; }
    int KB = K / 32;
    int TOT = (NC / 16) * KB * 64;
    if (idx >= TOT) return;
    int lane = idx & 63;
    int kb = (idx >> 6) % KB;
    int ct = (idx >> 6) / KB;
    int n = ct * 16 + (lane & 15);
    int k0 = kb * 32 + (lane >> 4) * 8;
    u16* dst = O + (size_t)idx * 8;
#pragma unroll
    for (int j = 0; j < 8; j++) dst[j] = f2bf(B[(size_t)(k0 + j) * NC + n]);
}

// ---------------- CSR scan (wave-parallel) ----------------
__global__ __launch_bounds__(256) void scan_kernel(const int* __restrict__ deg, int* __restrict__ offs,
                                                   int* __restrict__ cursor, int n) {
    __shared__ int wsum[4];
    int t = threadIdx.x;
    int chunk = (n + 255) / 256;
    int lo = t * chunk, hi = lo + chunk;
    if (hi > n) hi = n;
    if (lo > n) lo = n;
    int s = 0;
    for (int i = lo; i < hi; i++) s += deg[i];
    // inclusive wave scan of s
    int v = s;
#pragma unroll
    for (int d = 1; d < 64; d <<= 1) {
        int nb = __shfl_up(v, d, 64);
        if ((t & 63) >= d) v += nb;
    }
    if ((t & 63) == 63) wsum[t >> 6] = v;
    __syncthreads();
    int woff = 0;
#pragma unroll
    for (int w = 0; w < 4; w++)
        if (w < (t >> 6)) woff += wsum[w];
    int run = woff + v - s;  // exclusive prefix for this thread's chunk
    for (int i = lo; i < hi; i++) {
        offs[i] = run;
        cursor[i] = run;
        run += deg[i];
    }
    if (t == 255) offs[n] = run;  // thread 255's chunk is clamped at n -> run == total
}

// ---------------- fused: emb GEMM -> 8KB LDS -> fc1 GEMM + elr1 (16-row tiles); fill tail ----------------
__global__ __launch_bounds__(256) void fused_emb_fc1(const u16* __restrict__ Ah, const u16* __restrict__ Bemb,
                                                     const float* __restrict__ bemb, const u16* __restrict__ Bfc1,
                                                     const float* __restrict__ al, const float* __restrict__ ar,
                                                     u16* __restrict__ hh, u16* __restrict__ feat1,
                                                     u16* __restrict__ el, u16* __restrict__ er,
                                                     const int* __restrict__ src, const int* __restrict__ dstv,
                                                     int* __restrict__ cursor, int* __restrict__ srcs,
                                                     int M, int NB, int E, int N) {
    if ((int)blockIdx.x >= NB) {  // ---- CSR fill tail (block-uniform branch; barriers below stay uniform) ----
        int i = ((int)blockIdx.x - NB) * 256 + (int)threadIdx.x;
        if (i < E) {
            unsigned d = (unsigned)dstv[i];
            if (d < (unsigned)N) {
                int p = atomicAdd(&cursor[d], 1);
                if ((unsigned)p < (unsigned)E) srcs[p] = src[i];
            }
        }
        return;
    }
    __shared__ u16 tile[16 * 256];  // 8 KB, reused: swizzled hh tile, then plain feat1 tile
    const int t = threadIdx.x;
    const int lane = t & 63, w = t >> 6;
    const int rb = (int)blockIdx.x * 16;
    const int m = lane & 15, q = lane >> 4;
    const int arow = rb + m;

    // ---- stage 1: emb GEMM (K=128), this wave's ct = w*4 .. w*4+3 ----
    short8 a0[4];
#pragma unroll
    for (int kb = 0; kb < 4; kb++) {
        if (arow < M) a0[kb] = *(const short8*)(Ah + (size_t)arow * 128 + kb * 32 + q * 8);
        else a0[kb] = (short8){0, 0, 0, 0, 0, 0, 0, 0};
    }
    const short8* B8 = (const short8*)Bemb;
#pragma unroll
    for (int ct2 = 0; ct2 < 4; ct2++) {
        const int ct = w * 4 + ct2;
        f32x4 acc = {0.f, 0.f, 0.f, 0.f};
#pragma unroll
        for (int kb = 0; kb < 4; kb++)
            acc = __builtin_amdgcn_mfma_f32_16x16x32_bf16(a0[kb], B8[(ct * 4 + kb) * 64 + lane], acc, 0, 0, 0);
        float bv = bemb[ct * 16 + m];
#pragma unroll
        for (int r = 0; r < 4; r++) {
            int rl = q * 4 + r;
            int ro = rb + rl;
            u16 hv = 0;
            if (ro < M) {
                hv = f2bf(acc[r] + bv);
                hh[(size_t)ro * 256 + ct * 16 + m] = hv;
            }
            int byte = rl * 512 + (ct * 16 + m) * 2;
            tile[(byte ^ ((rl & 7) << 4)) >> 1] = hv;  // XOR-swizzle: b128 reads below are ~2-way (free)
        }
    }
    __syncthreads();

    // ---- stage 2: fc1 A-fragments straight from LDS (no global hh re-read) ----
    short8 af[8];
    {
        int rl = m;
#pragma unroll
        for (int kb = 0; kb < 8; kb++) {
            int byte = rl * 512 + kb * 64 + q * 16;
            af[kb] = *(const short8*)(tile + ((byte ^ ((rl & 7) << 4)) >> 1));
        }
    }
    __syncthreads();  // all af reads drained before tile is overwritten as feat1 tile

    const short8* Bf = (const short8*)Bfc1;
#pragma unroll
    for (int ct2 = 0; ct2 < 4; ct2++) {
        const int ct = w * 4 + ct2;
        f32x4 acc = {0.f, 0.f, 0.f, 0.f};
#pragma unroll
        for (int kb = 0; kb < 8; kb++)
            acc = __builtin_amdgcn_mfma_f32_16x16x32_bf16(af[kb], Bf[(ct * 8 + kb) * 64 + lane], acc, 0, 0, 0);
#pragma unroll
        for (int r = 0; r < 4; r++) {
            int rl = q * 4 + r;
            int ro = rb + rl;
            u16 v = 0;
            if (ro < M) {
                v = f2bf(acc[r]);
                feat1[(size_t)ro * 256 + ct * 16 + m] = v;
            }
            tile[rl * 256 + ct * 16 + m] = v;  // plain layout for elr epilogue
        }
    }
    __syncthreads();

    // ---- stage 3: el/er epilogue from feat1 tile (16 nodes x 8 heads = 128 tasks) ----
    if (t < 128) {
        int nl = t >> 3, h2 = t & 7;
        int node = rb + nl;
        if (node < M) {
            float a_ = 0.f, b_ = 0.f;
#pragma unroll
            for (int d = 0; d < 32; d++) {
                float fv = bf2f(tile[nl * 256 + h2 * 32 + d]);
                a_ += fv * al[h2 * 32 + d];
                b_ += fv * ar[h2 * 32 + d];
            }
            el[node * 8 + h2] = f2bf(a_);
            er[node * 8 + h2] = f2bf(b_);
        }
    }
}

// exp(leaky_relu(l)); logits O(0.1), max-subtraction unnecessary (identical ratios)
__device__ __forceinline__ float edgew(float l) {
    l = (l > 0.f) ? l : 0.2f * l;
    l = fminf(fmaxf(l, -30.f), 30.f);
    return __expf(l);
}

// ---------------- agg1: dual 32-lane edge streams + SHARDED bn-stats epilogue (R21) ----------------
// Core identical to R20. Epilogue: block reduces its 4 nodes' bf16-rounded outputs to
// per-column (sum,sumsq) in LDS, then 512 atomicAdds into stats_sh[bid&63][512]
// (2500 blocks / 64 shards = ~39 serialized RMWs per address).
__global__ __launch_bounds__(256) void agg1_fused(const u16* __restrict__ feat, const u16* __restrict__ el,
                                                  const u16* __restrict__ er, const int* __restrict__ offs,
                                                  const int* __restrict__ srcs, u16* __restrict__ rst,
                                                  float* __restrict__ stats_sh, int N, int E) {
    __shared__ float psum[4][256], psq[4][256];  // 8 KB
    const int t = threadIdx.x;
    const int wv = t >> 6;
    const int node = blockIdx.x * 4 + wv;
    const int lane = t & 63;
    const int half = lane >> 5;
    const int sl = lane & 31;
    const int h = sl >> 2;
    const bool valid = node < N;
    int beg = 0, end = 0;
    float ern = 0.f;
    if (valid) {
        beg = offs[node];
        end = offs[node + 1];
        if (beg < 0) beg = 0;
        if (end > E) end = E;
        ern = bf2f(er[node * 8 + h]);
    }
    int cnt = end - beg;
    if (cnt < 0) cnt = 0;
    float acc[8] = {0.f, 0.f, 0.f, 0.f, 0.f, 0.f, 0.f, 0.f};
    float sw = 0.f;
    const int myCnt = (cnt - half + 1) >> 1;  // edges in this half's stream
    const int jb = beg + half;
    int k = 0;
    int k4 = myCnt & ~3;
    for (; k < k4; k += 4) {  // 4-deep pipeline per half (8 edges in flight per wave)
        int j0 = jb + 2 * k;
        int s0 = srcs[j0], s1 = srcs[j0 + 2], s2 = srcs[j0 + 4], s3 = srcs[j0 + 6];
        unsigned c0 = (unsigned)s0 < (unsigned)N, c1 = (unsigned)s1 < (unsigned)N;
        unsigned c2 = (unsigned)s2 < (unsigned)N, c3 = (unsigned)s3 < (unsigned)N;
        s0 = c0 ? s0 : 0; s1 = c1 ? s1 : 0; s2 = c2 ? s2 : 0; s3 = c3 ? s3 : 0;
        u16 e0 = el[s0 * 8 + h], e1 = el[s1 * 8 + h], e2 = el[s2 * 8 + h], e3 = el[s3 * 8 + h];
        short8 f0 = *(const short8*)(feat + (size_t)s0 * 256 + sl * 8);
        short8 f1 = *(const short8*)(feat + (size_t)s1 * 256 + sl * 8);
        short8 f2 = *(const short8*)(feat + (size_t)s2 * 256 + sl * 8);
        short8 f3 = *(const short8*)(feat + (size_t)s3 * 256 + sl * 8);
        float w0 = c0 ? edgew(bf2f(e0) + ern) : 0.f;
        float w1 = c1 ? edgew(bf2f(e1) + ern) : 0.f;
        float w2 = c2 ? edgew(bf2f(e2) + ern) : 0.f;
        float w3 = c3 ? edgew(bf2f(e3) + ern) : 0.f;
        sw += w0 + w1 + w2 + w3;
#pragma unroll
        for (int q = 0; q < 8; q++)
            acc[q] += w0 * bf2f((u16)f0[q]) + w1 * bf2f((u16)f1[q]) + w2 * bf2f((u16)f2[q]) + w3 * bf2f((u16)f3[q]);
    }
    for (; k < myCnt; k++) {
        int j = jb + 2 * k;
        int s = srcs[j];
        if ((unsigned)s >= (unsigned)N) continue;
        float wv2 = edgew(bf2f(el[s * 8 + h]) + ern);
        short8 fv = *(const short8*)(feat + (size_t)s * 256 + sl * 8);
        sw += wv2;
#pragma unroll
        for (int q = 0; q < 8; q++) acc[q] += wv2 * bf2f((u16)fv[q]);
    }
    // combine even/odd halves (lane l <-> l^32)
#pragma unroll
    for (int q = 0; q < 8; q++) acc[q] += __shfl_xor(acc[q], 32, 64);
    sw += __shfl_xor(sw, 32, 64);
    if (half == 0) {
        float inv = 1.f / (sw + 1e-16f);
        short8 o;
#pragma unroll
        for (int q = 0; q < 8; q++) o[q] = (short)f2bf(acc[q] * inv);
        if (valid) *(short8*)(rst + (size_t)node * 256 + sl * 8) = o;
#pragma unroll
        for (int q = 0; q < 8; q++) {
            float v = valid ? bf2f((u16)o[q]) : 0.f;  // stats over bf16-rounded stored values
            psum[wv][sl * 8 + q] = v;
            psq[wv][sl * 8 + q] = v * v;
        }
    }
    __syncthreads();
    // column t reduced over the block's 4 nodes -> shard atomics
    float a = psum[0][t] + psum[1][t] + psum[2][t] + psum[3][t];
    float b = psq[0][t] + psq[1][t] + psq[2][t] + psq[3][t];
    float* shd = stats_sh + (size_t)(blockIdx.x & 63) * 512;
    atomicAdd(&shd[t], a);
    atomicAdd(&shd[256 + t], b);
}

// ---------------- fc2 GEMM: prologue reduces 64 stats shards; rest = R20 ----------------
__global__ __launch_bounds__(256) void gemm_fc2_fused(const u16* __restrict__ rst, const u16* __restrict__ hh,
                                                      const float* __restrict__ stats_sh, const float* __restrict__ g,
                                                      const float* __restrict__ b, const u16* __restrict__ Bsw,
                                                      const float* __restrict__ al2, const float* __restrict__ ar2,
                                                      float* __restrict__ feat2, float* __restrict__ el2,
                                                      float* __restrict__ er2, int M, float invN) {
    __shared__ float sc[256], sh[256];
    __shared__ float red[2][256];   // partial acc from waves 2,3 (per ct: 64 lanes x f32x4)
    __shared__ float tile[16][32];
    const int t = threadIdx.x;
    {
        float sum = 0.f, sq = 0.f;
#pragma unroll 8
        for (int s = 0; s < 64; s++) {
            sum += stats_sh[s * 512 + t];
            sq += stats_sh[s * 512 + 256 + t];
        }
        float mu = sum * invN;
        float var = fmaxf(sq * invN - mu * mu, 0.f);
        float s = g[t] * rsqrtf(var + 1e-5f);
        sc[t] = s;
        sh[t] = b[t] - mu * s;
    }
    __syncthreads();
    const int lane = t & 63, w = t >> 6;
    const int ct = w & 1, kh = w >> 1;
    const int rb = (int)blockIdx.x * 16;
    const int m = lane & 15, q = lane >> 4;
    const int row = rb + m;
    short8 a[4];
#pragma unroll
    for (int j = 0; j < 4; j++) {
        if (row < M) {
            int k0 = (kh * 4 + j) * 32 + q * 8;
            ushort4 r01 = *(const ushort4*)(rst + (size_t)row * 256 + k0);
            ushort4 r23 = *(const ushort4*)(rst + (size_t)row * 256 + k0 + 4);
            ushort4 h01 = *(const ushort4*)(hh + (size_t)row * 256 + k0);
            ushort4 h23 = *(const ushort4*)(hh + (size_t)row * 256 + k0 + 4);
            u16 rv[8] = {r01.x, r01.y, r01.z, r01.w, r23.x, r23.y, r23.z, r23.w};
            u16 hv[8] = {h01.x, h01.y, h01.z, h01.w, h23.x, h23.y, h23.z, h23.w};
            short8 av;
#pragma unroll
            for (int jj = 0; jj < 8; jj++) {
                int c = k0 + jj;
                float y = sc[c] * bf2f(rv[jj]) + sh[c];
                y = (y > 0.f) ? y : expm1f(y);
                av[jj] = (short)f2bf(bf2f(hv[jj]) + y);
            }
            a[j] = av;
        } else a[j] = (short8){0, 0, 0, 0, 0, 0, 0, 0};
    }
    const short8* B8 = (const short8*)Bsw;
    f32x4 acc = {0.f, 0.f, 0.f, 0.f};
#pragma unroll
    for (int j = 0; j < 4; j++)
        acc = __builtin_amdgcn_mfma_f32_16x16x32_bf16(a[j], B8[(ct * 8 + kh * 4 + j) * 64 + lane], acc, 0, 0, 0);
    if (kh == 1) *(f32x4*)&red[ct][lane * 4] = acc;
    __syncthreads();
    if (kh == 0) {
        f32x4 p = *(const f32x4*)&red[ct][lane * 4];
#pragma unroll
        for (int r = 0; r < 4; r++) {
            int rl = q * 4 + r;
            int ro = rb + rl;
            float v = 0.f;
            if (ro < M) {
                v = acc[r] + p[r];
                feat2[(size_t)ro * 32 + ct * 16 + m] = v;
            }
            tile[rl][ct * 16 + m] = v;
        }
    }
    __syncthreads();
    if (t < 16) {
        int node = rb + t;
        if (node < M) {
            float a_ = 0.f, b_ = 0.f;
#pragma unroll
            for (int d = 0; d < 32; d++) {
                float fv = tile[t][d];
                a_ += fv * al2[d];
                b_ += fv * ar2[d];
            }
            el2[node] = a_;
            er2[node] = b_;
        }
    }
}

// ---------------- agg2: 4-deep pipeline + SHARDED stats2 epilogue (R21) ----------------
__global__ __launch_bounds__(256) void agg2_fused(const float* __restrict__ feat, const float* __restrict__ el,
                                                  const float* __restrict__ er, const int* __restrict__ offs,
                                                  const int* __restrict__ srcs, float* __restrict__ rst,
                                                  float* __restrict__ stats2_sh, int N, int E) {
    __shared__ float ss[256], ss2[256];
    const int t = threadIdx.x;
    const int node = blockIdx.x * 8 + (t >> 5);
    const int d = t & 31;
    const bool valid = node < N;
    float v = 0.f;
    if (valid) {
        int beg = offs[node], end = offs[node + 1];
        if (beg < 0) beg = 0;
        if (end > E) end = E;
        float ern = er[node];
        float acc = 0.f, sw = 0.f;
        int j = beg;
        int end4 = beg + ((end - beg) & ~3);
        for (; j < end4; j += 4) {  // 4-deep software pipeline
            int s0 = srcs[j], s1 = srcs[j + 1], s2 = srcs[j + 2], s3 = srcs[j + 3];
            unsigned c0 = (unsigned)s0 < (unsigned)N, c1 = (unsigned)s1 < (unsigned)N;
            unsigned c2 = (unsigned)s2 < (unsigned)N, c3 = (unsigned)s3 < (unsigned)N;
            s0 = c0 ? s0 : 0; s1 = c1 ? s1 : 0; s2 = c2 ? s2 : 0; s3 = c3 ? s3 : 0;
            float e0 = el[s0], e1 = el[s1], e2 = el[s2], e3 = el[s3];
            float f0 = feat[(size_t)s0 * 32 + d];
            float f1 = feat[(size_t)s1 * 32 + d];
            float f2 = feat[(size_t)s2 * 32 + d];
            float f3 = feat[(size_t)s3 * 32 + d];
            float w0 = c0 ? edgew(e0 + ern) : 0.f;
            float w1 = c1 ? edgew(e1 + ern) : 0.f;
            float w2 = c2 ? edgew(e2 + ern) : 0.f;
            float w3 = c3 ? edgew(e3 + ern) : 0.f;
            sw += w0; acc += w0 * f0;
            sw += w1; acc += w1 * f1;
            sw += w2; acc += w2 * f2;
            sw += w3; acc += w3 * f3;
        }
        for (; j < end; j++) {
            int s = srcs[j];
            if ((unsigned)s >= (unsigned)N) continue;
            float wv = edgew(el[s] + ern);
            sw += wv;
            acc += wv * feat[(size_t)s * 32 + d];
        }
        v = acc / (sw + 1e-16f);
        rst[(size_t)node * 32 + d] = v;
    }
    ss[t] = valid ? v : 0.f;
    ss2[t] = valid ? v * v : 0.f;
    __syncthreads();
    if (t < 32) {
        float a = 0.f, b = 0.f;
#pragma unroll
        for (int rg = 0; rg < 8; rg++) {
            a += ss[rg * 32 + t];
            b += ss2[rg * 32 + t];
        }
        float* shd = stats2_sh + (size_t)(blockIdx.x & 31) * 64;
        atomicAdd(&shd[t], a);
        atomicAdd(&shd[32 + t], b);
    }
}

// ---------------- final bn + elu -> f32 out; prologue reduces 32 stats2 shards ----------------
__global__ __launch_bounds__(256) void bn_apply2(const float* __restrict__ rst, const float* __restrict__ stats2_sh,
                                                 const float* __restrict__ g, const float* __restrict__ b,
                                                 float* __restrict__ out, int total4, float invN) {
    __shared__ float st[64];
    int t = threadIdx.x;
    if (t < 64) {
        float a = 0.f;
#pragma unroll
        for (int s = 0; s < 32; s++) a += stats2_sh[s * 64 + t];
        st[t] = a;
    }
    __syncthreads();
    int idx = blockIdx.x * 256 + t;
    if (idx >= total4) return;
    float4 v = ((const float4*)rst)[idx];
    int c0 = (idx * 4) & 31;
    float r[4] = {v.x, v.y, v.z, v.w};
#pragma unroll
    for (int j = 0; j < 4; j++) {
        int c = c0 + j;
        float mu = st[c] * invN;
        float var = fmaxf(st[32 + c] * invN - mu * mu, 0.f);
        float y = g[c] * (r[j] - mu) * rsqrtf(var + 1e-5f) + b[c];
        r[j] = (y > 0.f) ? y : expm1f(y);
    }
    float4 o = {r[0], r[1], r[2], r[3]};
    ((float4*)out)[idx] = o;
}

extern "C" void kernel_launch(void* const* d_in, const int* in_sizes, int n_in, void* d_out, int out_size, void* d_ws,
                              size_t ws_size, hipStream_t stream) {
    const int N = out_size / ODIM;
    const int E = in_sizes[2];

    const int* src = (const int*)d_in[2];
    const int* dst = (const int*)d_in[3];
    const float* in_h = (const float*)d_in[0];
    const float* W_emb = (const float*)d_in[4];  const float* b_emb = (const float*)d_in[5];
    const float* fc1 = (const float*)d_in[18];   const float* al1 = (const float*)d_in[19];
    const float* ar1 = (const float*)d_in[20];
    const float* g1 = (const float*)d_in[21];    const float* b1 = (const float*)d_in[22];
    const float* fc2 = (const float*)d_in[23];   const float* al2 = (const float*)d_in[24];
    const float* ar2 = (const float*)d_in[25];
    const float* g2 = (const float*)d_in[26];    const float* b2 = (const float*)d_in[27];
    float* out = (float*)d_out;

    // ---- ws layout (~26 MB) ----
    char* base = (char*)d_ws;
    size_t off = 0;
    auto alloc = [&](size_t bytes) { void* p = base + off; off += (bytes + 63) & ~63ull; return p; };
    const size_t ZBYTES = (size_t)N * 4 + 64 * 512 * 4 + 32 * 64 * 4;  // deg + stats shards + stats2 shards
    char* zb   = (char*)alloc(ZBYTES);
    int* deg   = (int*)zb;
    float* stats_sh  = (float*)(zb + (size_t)N * 4);
    float* stats2_sh = stats_sh + 64 * 512;
    int* offs  = (int*)alloc((size_t)(N + 1) * 4);
    int* cursor = (int*)alloc((size_t)N * 4);
    int* srcs  = (int*)alloc((size_t)E * 4);
    u16* Ah    = (u16*)alloc((size_t)N * 128 * 2);
    u16* Bemb  = (u16*)alloc((size_t)128 * 256 * 2);
    u16* Bfc1  = (u16*)alloc((size_t)256 * 256 * 2);
    u16* Bfc2  = (u16*)alloc((size_t)256 * 32 * 2);
    u16* hh    = (u16*)alloc((size_t)N * HDIM * 2);
    u16* feat1 = (u16*)alloc((size_t)N * HDIM * 2);
    u16* el1   = (u16*)alloc((size_t)N * 8 * 2);
    u16* er1   = (u16*)alloc((size_t)N * 8 * 2);
    u16* rst   = (u16*)alloc((size_t)N * HDIM * 2);
    float* feat2 = (float*)alloc((size_t)N * 32 * 4);
    float* el2 = (float*)alloc((size_t)N * 4);
    float* er2 = (float*)alloc((size_t)N * 4);
    float* rst2 = (float*)alloc((size_t)N * 32 * 4);

    const int NB16 = (N + 15) / 16;
    const int NBF = (E + 255) / 256;  // fill tail blocks

    hipMemsetAsync(zb, 0, ZBYTES, stream);
    prep_kernel<<<dim3((N * 128 / 4 + 255) / 256, 5), 256, 0, stream>>>(in_h, W_emb, fc1, fc2, dst, deg,
                                                                        Ah, Bemb, Bfc1, Bfc2, N * 128 / 4, E, N);
    scan_kernel<<<1, 256, 0, stream>>>(deg, offs, cursor, N);
    fused_emb_fc1<<<NB16 + NBF, 256, 0, stream>>>(Ah, Bemb, b_emb, Bfc1, al1, ar1, hh, feat1, el1, er1,
                                                  src, dst, cursor, srcs, N, NB16, E, N);
    agg1_fused<<<(N + 3) / 4, 256, 0, stream>>>(feat1, el1, er1, offs, srcs, rst, stats_sh, N, E);
    gemm_fc2_fused<<<NB16, 256, 0, stream>>>(rst, hh, stats_sh, g1, b1, Bfc2, al2, ar2, feat2, el2, er2, N, 1.f / N);
    agg2_fused<<<(N + 7) / 8, 256, 0, stream>>>(feat2, el2, er2, offs, srcs, rst2, stats2_sh, N, E);
    bn_apply2<<<(N * 8 + 255) / 256, 256, 0, stream>>>(rst2, stats2_sh, g2, b2, out, N * 8, 1.f / N);
}